// Round 6
// baseline (3623.507 us; speedup 1.0000x reference)
//
#include <hip/hip_runtime.h>
#include <stdint.h>

// ---------------------------------------------------------------------------
// 2-layer LSTM (T=256, B=256, F=128, H=1024) for MI355X (gfx950).
// R12: chunk-granular producer->consumer pipeline. R11 exonerated the sync
// mechanism; the cost is the serial step tail (wait-all -> stage-64KB ->
// drain -> barrier -> MFMA) convoying on the slowest of 32 producers.
// The h-dependency decomposes: j-iter j of wave kh consumes exactly producer
// (kh*16+j)'s 32 h-cols. So:
//   - As becomes chunk-major [32][32][32] bf16 (2KB/chunk, 64KB, no pad);
//     hx/hpp become tile-blocked [slot][32 blk][256 row][32 col] so a chunk
//     is 2KB contiguous -> 2x1KB global_load_lds, fully coalesced.
//   - wave (g,kh) stages its 4 chunks {kh*16+g+4q}, vmcnt(0), one LDS
//     release-flag. Consumers spin on <=3 peer flags (self chunks by program
//     order), 16 MFMAs between checks. whh register slots load-permuted into
//     consume order (compile-time reg indices).
//   - sync C gone (flags gate As validity; syncA/syncB fence As reuse);
//     external poll is 4 stamps (vector-4 lanes), not 32. Skew + staging
//     overlap MFMA on arrived chunks.
// Fast/heavy collapse to one flow: poll -> (vl1_inv | agent acquire) ->
// stage. Probe/stamp/generation scheme unchanged from R11. Spins bounded.
// ---------------------------------------------------------------------------

typedef __bf16 bf16x8 __attribute__((ext_vector_type(8)));
typedef float  f32x4  __attribute__((ext_vector_type(4)));
typedef unsigned short ushort8v __attribute__((ext_vector_type(8)));
typedef unsigned short ushort4v __attribute__((ext_vector_type(4)));
typedef unsigned short ushort2v __attribute__((ext_vector_type(2)));
typedef __attribute__((address_space(1))) unsigned int as1_u32;
typedef __attribute__((address_space(3))) unsigned int as3_u32;

#define T_STEPS 256
#define BATCH   256
#define HDIM    1024
#define GDIM    4096
#define FDIM    128
#define HXSLOT  (BATCH * HDIM)   // elements per blocked h slot (512KB)

static __device__ __forceinline__ float bf2f(unsigned short u) {
  union { unsigned int i; float f; } v; v.i = ((unsigned int)u) << 16; return v.f;
}
static __device__ __forceinline__ unsigned short f2bf(float f) {
  return __builtin_bit_cast(unsigned short, (__bf16)f);
}
static __device__ __forceinline__ float sigm(float x) { return 1.f / (1.f + __expf(-x)); }
static __device__ __forceinline__ float tanh_f(float x) { return 2.f / (1.f + __expf(-2.f * x)) - 1.f; }

static __device__ __forceinline__ void vl1_inv() {
  asm volatile("buffer_inv" ::: "memory");
}

__global__ void conv_bf16(const float* __restrict__ s, unsigned short* __restrict__ d, int n) {
  int i = blockIdx.x * 256 + threadIdx.x;
  if (i < n) d[i] = f2bf(s[i]);
}

__global__ void diag_kernel(float* out, int n, float v) {
  int i = blockIdx.x * 256 + threadIdx.x;
  if (i < n) out[i] = v;
}

// ------------------------- stamps / polls / flags ----------------------------
// stamps = bar + mi*1024 (u32): producer ni's stamp at stamps[ni*32] (128B
// apart, one line each). Monotonic; 0xAAAAAAAA poison reads negative.
__device__ __forceinline__ void post_stamp(unsigned int* st, unsigned int gen, bool fast) {
  if (!fast) __builtin_amdgcn_fence(__ATOMIC_RELEASE, "agent");
  __hip_atomic_store(st, gen, __ATOMIC_RELAXED, __HIP_MEMORY_SCOPE_AGENT);
}

// All-wave poll of all 32 stamps (probe only): lane l polls stamp[l&31].
__device__ __forceinline__ void poll_all(unsigned int* stamps, unsigned int target) {
  unsigned int* p = stamps + (threadIdx.x & 31) * 32;
  for (unsigned int it = 0; it < (1u << 15); ++it) {
    unsigned int gv = __hip_atomic_load(p, __ATOMIC_RELAXED, __HIP_MEMORY_SCOPE_AGENT);
    if (__all((int)(gv - target) >= 0)) return;
    if (it > 16) __builtin_amdgcn_s_sleep(1);
  }
}

// Per-wave poll of this wave's 4 producers: lane l polls producer
// kh*16 + g + 4*(l&3).
__device__ __forceinline__ void poll_mine(unsigned int* stamps, int g, int kh, unsigned int target) {
  unsigned int* p = stamps + (kh * 16 + g + 4 * ((int)threadIdx.x & 3)) * 32;
  for (unsigned int it = 0; it < (1u << 15); ++it) {
    unsigned int gv = __hip_atomic_load(p, __ATOMIC_RELAXED, __HIP_MEMORY_SCOPE_AGENT);
    if (__all((int)(gv - target) >= 0)) return;
    if (it > 16) __builtin_amdgcn_s_sleep(1);
  }
}

// LDS flag spin (workgroup acquire; all lanes same addr -> broadcast).
__device__ __forceinline__ void lds_spin(unsigned int* f, unsigned int need) {
  for (unsigned int it = 0; it < (1u << 15); ++it) {
    unsigned int v = __hip_atomic_load(f, __ATOMIC_ACQUIRE, __HIP_MEMORY_SCOPE_WORKGROUP);
    if ((int)(v - need) >= 0) return;
    if (it > 8) __builtin_amdgcn_s_sleep(1);
  }
}

// Stage this wave's 4 chunks (2KB each, contiguous in blocked h) into
// chunk-major As via global_load_lds width-16 (2 x 1KB per chunk).
__device__ __forceinline__ void stage_chunks(const unsigned short* __restrict__ hsrc,
                                             unsigned short* AsPtr, int r0, int g, int kh, int lane) {
  #pragma unroll
  for (int q = 0; q < 4; ++q) {
    int c = kh * 16 + g + 4 * q;
    const char* src = (const char*)(hsrc + (size_t)c * 8192 + r0 * 32);
    char* dst = (char*)AsPtr + c * 2048;
    __builtin_amdgcn_global_load_lds((const as1_u32*)(src + lane * 16), (as3_u32*)dst, 16, 0, 0);
    __builtin_amdgcn_global_load_lds((const as1_u32*)(src + 1024 + lane * 16), (as3_u32*)(dst + 1024), 16, 0, 0);
  }
}

// --------------------------- gemm_bt: C = A @ B^T ---------------------------
__global__ __launch_bounds__(256) void gemm_bt_xw(
    const unsigned short* __restrict__ A,
    const unsigned short* __restrict__ B,
    unsigned short* __restrict__ xw,
    int K)
{
  const int tid = threadIdx.x, lane = tid & 63, w = tid >> 6;
  const int m0 = blockIdx.x * 128;
  const int n0 = blockIdx.y * 128;
  __shared__ unsigned short As[128 * 64];
  __shared__ unsigned short Bs[128 * 64];
  const int mrow0 = (w & 1) * 64, ncol0 = (w >> 1) * 64;
  const int quad = lane >> 4;

  f32x4 acc[4][4];
  #pragma unroll
  for (int i = 0; i < 4; ++i)
    #pragma unroll
    for (int j = 0; j < 4; ++j) acc[i][j] = f32x4{0.f, 0.f, 0.f, 0.f};

  const int kiter = K >> 6;
  for (int ki = 0; ki < kiter; ++ki) {
    const int k0 = ki * 64;
    __syncthreads();
    #pragma unroll
    for (int i = 0; i < 4; ++i) {
      int obase = (w * 4 + i) * 1024;          // wave-uniform LDS byte base
      int o = obase + lane * 16;
      int row = o >> 7; int kb = o & 127;
      const char* ga = (const char*)A + ((size_t)(m0 + row) * K + k0) * 2 + kb;
      const char* gb = (const char*)B + ((size_t)(n0 + row) * K + k0) * 2 + kb;
      __builtin_amdgcn_global_load_lds((const as1_u32*)ga, (as3_u32*)((char*)As + obase), 16, 0, 0);
      __builtin_amdgcn_global_load_lds((const as1_u32*)gb, (as3_u32*)((char*)Bs + obase), 16, 0, 0);
    }
    __syncthreads();
    #pragma unroll
    for (int kk = 0; kk < 2; ++kk) {
      bf16x8 af[4], bfr[4];
      #pragma unroll
      for (int mt = 0; mt < 4; ++mt)
        af[mt] = *(const bf16x8*)(As + (mrow0 + mt * 16 + (lane & 15)) * 64 + kk * 32 + quad * 8);
      #pragma unroll
      for (int nt = 0; nt < 4; ++nt)
        bfr[nt] = *(const bf16x8*)(Bs + (ncol0 + nt * 16 + (lane & 15)) * 64 + kk * 32 + quad * 8);
      #pragma unroll
      for (int mt = 0; mt < 4; ++mt)
        #pragma unroll
        for (int nt = 0; nt < 4; ++nt)
          acc[mt][nt] = __builtin_amdgcn_mfma_f32_16x16x32_bf16(af[mt], bfr[nt], acc[mt][nt], 0, 0, 0);
    }
  }
  #pragma unroll
  for (int mt = 0; mt < 4; ++mt) {
    int m = m0 + mrow0 + mt * 16 + quad * 4;
    int tl = m >> 8, b = m & 255;
    #pragma unroll
    for (int nt = 0; nt < 4; ++nt) {
      int col = n0 + ncol0 + nt * 16 + (lane & 15);
      ushort4v v;
      v.x = f2bf(acc[mt][nt][0]); v.y = f2bf(acc[mt][nt][1]);
      v.z = f2bf(acc[mt][nt][2]); v.w = f2bf(acc[mt][nt][3]);
      *(ushort4v*)(xw + ((size_t)tl * GDIM + col) * BATCH + b) = v;
    }
  }
}

// ---------------- probe: validate intra-XCD visibility for this group --------
__device__ __forceinline__ bool probe_chk(unsigned int* probeBuf, unsigned int* stamps,
                                          unsigned int salt, unsigned int target,
                                          unsigned int* flagLds) {
  const int wg = blockIdx.x, mi = wg & 7, ni = wg >> 3;
  const int tid = threadIdx.x;
  if (tid == 0) probeBuf[wg * 32] = salt ^ (unsigned int)wg;
  __syncthreads();   // drains token store to L2
  if (tid == 0)
    __hip_atomic_store(stamps + ni * 32, target, __ATOMIC_RELAXED, __HIP_MEMORY_SCOPE_AGENT);
  poll_all(stamps, target);
  vl1_inv();
  if (tid == 0) {
    unsigned int bad = 0;
    for (int k = 0; k < 32; ++k) {
      int member = mi + 8 * k;
      unsigned int v = probeBuf[member * 32];
      if (v != (salt ^ (unsigned int)member)) bad = 1;
    }
    *flagLds = bad;
  }
  __syncthreads();
  return (*flagLds == 0);
}

// --------------------------- layer 0: fused persistent chunk -----------------
// 256 WGs x 512 thr, 1/CU. WG (mi=wg&7, ni=wg>>3): rows [32mi,+32), cols [32ni,+32).
// Wave wv: gate g=wv&3, K-half kh=wv>>2. whh[2][16] slots in CONSUME order.
__global__ __launch_bounds__(512, 2) void lstm_layer0_kernel(
    const unsigned short* __restrict__ xbf,  // (T,B,F) bf16
    const float* __restrict__ Wih,           // (4096,128) fp32
    const float* __restrict__ Whh,           // (4096,1024) fp32
    const float* __restrict__ bih,
    const float* __restrict__ bhh,
    unsigned short* __restrict__ slab,       // (ch_len+1, B, H) bf16 row-major, gemm feed
    unsigned short* __restrict__ hx,         // 2-slot blocked ping-pong [32][256][32]
    float* __restrict__ cstate,              // (B,H) fp32
    int t0, int ch_len, unsigned int gen_base,
    float* __restrict__ dout_h,
    float* __restrict__ dout_c,
    unsigned int* __restrict__ bar,
    unsigned int* __restrict__ probe)
{
  const int tid = threadIdx.x, lane = tid & 63, wv = tid >> 6;   // wv 0..7
  const int quad = lane >> 4, l15 = lane & 15;
  const int g = wv & 3, kh = wv >> 2;
  const int wg = blockIdx.x;
  const int mi = wg & 7, ni = wg >> 3;
  const int r0 = mi * 32, hc0 = ni * 32;
  unsigned int* stamps = bar + mi * 1024;

  __shared__ unsigned short As[32 * 1024];   // chunk-major: [32 chunks][32r][32c]
  __shared__ float gbuf[8][32][36];
  __shared__ unsigned int cflag[8];          // per-(kh,g) stager flags
  __shared__ unsigned int flagLds;

  if (tid < 8) cflag[tid] = 0;

  // W_hh fragment, slots permuted into consume order:
  // slot sl -> chunk j(sl) = ((g + (sl>>2)) & 3) + 4*(sl&3)
  bf16x8 whh[2][16];
  #pragma unroll
  for (int nt = 0; nt < 2; ++nt) {
    #pragma unroll
    for (int sl = 0; sl < 16; ++sl) {
      int jj = ((g + (sl >> 2)) & 3) + 4 * (sl & 3);
      const float* wrow = Whh + (size_t)(g * HDIM + hc0 + nt * 16 + l15) * HDIM + kh * 512 + jj * 32 + quad * 8;
      f32x4 f0 = *(const f32x4*)(wrow);
      f32x4 f1 = *(const f32x4*)(wrow + 4);
      bf16x8 r;
      r[0] = (__bf16)f0[0]; r[1] = (__bf16)f0[1]; r[2] = (__bf16)f0[2]; r[3] = (__bf16)f0[3];
      r[4] = (__bf16)f1[0]; r[5] = (__bf16)f1[1]; r[6] = (__bf16)f1[2]; r[7] = (__bf16)f1[3];
      whh[nt][sl] = r;
    }
  }
  // W_ih fragment: K=128 split across kh (64 each)
  bf16x8 wih[2][2];
  #pragma unroll
  for (int nt = 0; nt < 2; ++nt) {
    const float* wrow = Wih + (size_t)(g * HDIM + hc0 + nt * 16 + l15) * FDIM + kh * 64 + quad * 8;
    #pragma unroll
    for (int kk = 0; kk < 2; ++kk) {
      f32x4 f0 = *(const f32x4*)(wrow + kk * 32);
      f32x4 f1 = *(const f32x4*)(wrow + kk * 32 + 4);
      bf16x8 r;
      r[0] = (__bf16)f0[0]; r[1] = (__bf16)f0[1]; r[2] = (__bf16)f0[2]; r[3] = (__bf16)f0[3];
      r[4] = (__bf16)f1[0]; r[5] = (__bf16)f1[1]; r[6] = (__bf16)f1[2]; r[7] = (__bf16)f1[3];
      wih[nt][kk] = r;
    }
  }

  const int hcl = tid & 31, rg2 = tid >> 5;
  float bias[4];
  #pragma unroll
  for (int b4 = 0; b4 < 4; ++b4)
    bias[b4] = bih[b4 * HDIM + hc0 + hcl] + bhh[b4 * HDIM + hc0 + hcl];

  float c[2];
  #pragma unroll
  for (int r = 0; r < 2; ++r)
    c[r] = (t0 == 0) ? 0.f : cstate[(size_t)(r0 + rg2 * 2 + r) * HDIM + hc0 + hcl];

  unsigned int salt = 0x9E3779B9u ^ (gen_base * 2654435761u);
  bool fast = probe_chk(probe, stamps, salt, gen_base + 1u, &flagLds);

  const int tend = t0 + ch_len;

  // prologue: cross-kernel h stage (blocked hx from prev dispatch)
  if (t0 > 0) {
    stage_chunks(hx + (size_t)((t0 - 1) & 1) * HXSLOT, As, r0, g, kh, lane);
    asm volatile("s_waitcnt vmcnt(0)" ::: "memory");
    if (lane == 0)
      __hip_atomic_store(&cflag[kh * 4 + g], gen_base + 1u, __ATOMIC_RELEASE, __HIP_MEMORY_SCOPE_WORKGROUP);
  }

  // prologue: x-projection for the first step
  f32x4 acc[2][2];
  #pragma unroll
  for (int mt = 0; mt < 2; ++mt)
    #pragma unroll
    for (int nt = 0; nt < 2; ++nt) acc[mt][nt] = f32x4{0.f, 0.f, 0.f, 0.f};
  #pragma unroll
  for (int j = 0; j < 2; ++j) {
    bf16x8 af[2];
    #pragma unroll
    for (int mt = 0; mt < 2; ++mt)
      af[mt] = *(const bf16x8*)(xbf + (size_t)(t0 * BATCH + r0 + mt * 16 + l15) * FDIM + kh * 64 + j * 32 + quad * 8);
    #pragma unroll
    for (int mt = 0; mt < 2; ++mt)
      #pragma unroll
      for (int nt = 0; nt < 2; ++nt)
        acc[mt][nt] = __builtin_amdgcn_mfma_f32_16x16x32_bf16(af[mt], wih[nt][j], acc[mt][nt], 0, 0, 0);
  }

  #pragma unroll 1
  for (int t = t0; t < tend; ++t) {
    if (t > 0) {
      // consume 16 chunks in 4 stager-batches; self batch needs no spin.
      const unsigned int need = gen_base + 1u + (unsigned int)(t - t0);
      #pragma unroll
      for (int sl = 0; sl < 16; ++sl) {
        const int s = sl >> 2, q = sl & 3;
        int sg = (g + s) & 3;
        if (q == 0 && s > 0) lds_spin(&cflag[kh * 4 + sg], need);
        int cidx = kh * 16 + sg + 4 * q;
        bf16x8 af[2];
        #pragma unroll
        for (int mt = 0; mt < 2; ++mt)
          af[mt] = *(const bf16x8*)((const char*)As + cidx * 2048 + (mt * 16 + l15) * 64 + quad * 16);
        #pragma unroll
        for (int mt = 0; mt < 2; ++mt)
          #pragma unroll
          for (int nt = 0; nt < 2; ++nt)
            acc[mt][nt] = __builtin_amdgcn_mfma_f32_16x16x32_bf16(af[mt], whh[nt][sl], acc[mt][nt], 0, 0, 0);
      }
    }

    #pragma unroll
    for (int mt = 0; mt < 2; ++mt)
      #pragma unroll
      for (int nt = 0; nt < 2; ++nt) {
        int hl = nt * 16 + l15;
        int rq = mt * 16 + quad * 4;
        *(f32x4*)&gbuf[wv][hl][rq] = acc[mt][nt];
      }
    __syncthreads();   // (A) gbuf visible; all As reads of step t complete

    unsigned short* hdst = slab + (size_t)(t - t0 + 1) * (BATCH * HDIM);
    unsigned short* hxd  = hx + (size_t)(t & 1) * HXSLOT;
    #pragma unroll
    for (int r = 0; r < 2; ++r) {
      int row = rg2 * 2 + r;
      float gi = gbuf[0][hcl][row] + gbuf[4][hcl][row] + bias[0];
      float gf = gbuf[1][hcl][row] + gbuf[5][hcl][row] + bias[1];
      float gg = gbuf[2][hcl][row] + gbuf[6][hcl][row] + bias[2];
      float go = gbuf[3][hcl][row] + gbuf[7][hcl][row] + bias[3];
      float iv = sigm(gi), fv = sigm(gf), gv = tanh_f(gg), ov = sigm(go);
      float cn = fv * c[r] + iv * gv;
      c[r] = cn;
      float hv = ov * tanh_f(cn);
      unsigned short hb = f2bf(hv);
      // blocked hx: block ni, row r0+row, col hcl
      hxd[ni * 8192 + (r0 + row) * 32 + hcl] = hb;
      int gidx = (r0 + row) * HDIM + hc0 + hcl;
      hdst[gidx] = hb;       // gemm feed (row-major)
      if (t == tend - 1) cstate[gidx] = cn;
      if (t == T_STEPS - 1) { dout_h[gidx] = hv; dout_c[gidx] = cn; }
    }
    __syncthreads();   // (B) drains h stores (vmcnt 0) -> visible at L2

    if (t != tend - 1) {
      const unsigned int tgt = gen_base + 2u + (unsigned int)(t - t0);
      if (tid == 0) post_stamp(stamps + ni * 32, tgt, fast);

      // hoisted: x-projection for step t+1 (independent of h(t))
      #pragma unroll
      for (int mt = 0; mt < 2; ++mt)
        #pragma unroll
        for (int nt = 0; nt < 2; ++nt) acc[mt][nt] = f32x4{0.f, 0.f, 0.f, 0.f};
      #pragma unroll
      for (int j = 0; j < 2; ++j) {
        bf16x8 af[2];
        #pragma unroll
        for (int mt = 0; mt < 2; ++mt)
          af[mt] = *(const bf16x8*)(xbf + (size_t)((t + 1) * BATCH + r0 + mt * 16 + l15) * FDIM + kh * 64 + j * 32 + quad * 8);
        #pragma unroll
        for (int mt = 0; mt < 2; ++mt)
          #pragma unroll
          for (int nt = 0; nt < 2; ++nt)
            acc[mt][nt] = __builtin_amdgcn_mfma_f32_16x16x32_bf16(af[mt], wih[nt][j], acc[mt][nt], 0, 0, 0);
      }

      // exchange: wait only for MY 4 producers, stage my chunks, flag.
      poll_mine(stamps, g, kh, tgt);
      if (fast) vl1_inv();
      else __builtin_amdgcn_fence(__ATOMIC_ACQUIRE, "agent");
      stage_chunks(hx + (size_t)(t & 1) * HXSLOT, As, r0, g, kh, lane);
      asm volatile("s_waitcnt vmcnt(0)" ::: "memory");
      if (lane == 0)
        __hip_atomic_store(&cflag[kh * 4 + g], tgt, __ATOMIC_RELEASE, __HIP_MEMORY_SCOPE_WORKGROUP);
    }
  }
}

// --------------------------- layer 1: persistent chunk ----------------------
__global__ __launch_bounds__(512, 2) void lstm_layer1_kernel(
    const unsigned short* __restrict__ xw,   // (ch_len, 4096, 256) bf16
    const float* __restrict__ Whh,
    const float* __restrict__ bih,
    const float* __restrict__ bhh,
    unsigned short* __restrict__ hpp,        // 2-slot blocked ping-pong
    float* __restrict__ cstate,
    int t0, int ch_len, unsigned int gen_base,
    unsigned short* __restrict__ h1t0,
    float* __restrict__ dout_h,
    float* __restrict__ dout_c,
    unsigned int* __restrict__ bar,
    unsigned int* __restrict__ probe)
{
  const int tid = threadIdx.x, lane = tid & 63, wv = tid >> 6;
  const int quad = lane >> 4, l15 = lane & 15;
  const int g = wv & 3, kh = wv >> 2;
  const int wg = blockIdx.x;
  const int mi = wg & 7, ni = wg >> 3;
  const int r0 = mi * 32, hc0 = ni * 32;
  unsigned int* stamps = bar + mi * 1024;

  __shared__ unsigned short As[32 * 1024];
  __shared__ float gbuf[8][32][36];
  __shared__ unsigned int cflag[8];
  __shared__ unsigned int flagLds;

  if (tid < 8) cflag[tid] = 0;

  bf16x8 whh[2][16];
  #pragma unroll
  for (int nt = 0; nt < 2; ++nt) {
    #pragma unroll
    for (int sl = 0; sl < 16; ++sl) {
      int jj = ((g + (sl >> 2)) & 3) + 4 * (sl & 3);
      const float* wrow = Whh + (size_t)(g * HDIM + hc0 + nt * 16 + l15) * HDIM + kh * 512 + jj * 32 + quad * 8;
      f32x4 f0 = *(const f32x4*)(wrow);
      f32x4 f1 = *(const f32x4*)(wrow + 4);
      bf16x8 r;
      r[0] = (__bf16)f0[0]; r[1] = (__bf16)f0[1]; r[2] = (__bf16)f0[2]; r[3] = (__bf16)f0[3];
      r[4] = (__bf16)f1[0]; r[5] = (__bf16)f1[1]; r[6] = (__bf16)f1[2]; r[7] = (__bf16)f1[3];
      whh[nt][sl] = r;
    }
  }

  const int hcl = tid & 31, rg2 = tid >> 5;
  float bias[4];
  #pragma unroll
  for (int b4 = 0; b4 < 4; ++b4)
    bias[b4] = bih[b4 * HDIM + hc0 + hcl] + bhh[b4 * HDIM + hc0 + hcl];

  float c[2];
  #pragma unroll
  for (int r = 0; r < 2; ++r)
    c[r] = (t0 == 0) ? 0.f : cstate[(size_t)(r0 + rg2 * 2 + r) * HDIM + hc0 + hcl];

  unsigned int salt = 0xB5297A4Du ^ (gen_base * 2654435761u);
  bool fast = probe_chk(probe, stamps, salt, gen_base + 1u, &flagLds);

  const int tend = t0 + ch_len;

  if (t0 > 0) {
    stage_chunks(hpp + (size_t)((t0 - 1) & 1) * HXSLOT, As, r0, g, kh, lane);
    asm volatile("s_waitcnt vmcnt(0)" ::: "memory");
    if (lane == 0)
      __hip_atomic_store(&cflag[kh * 4 + g], gen_base + 1u, __ATOMIC_RELEASE, __HIP_MEMORY_SCOPE_WORKGROUP);
  }

  float xwv[4][2];
  #pragma unroll
  for (int g4 = 0; g4 < 4; ++g4) {
    const unsigned short* xp =
        xw + ((size_t)0 * GDIM + g4 * HDIM + hc0 + hcl) * BATCH + r0 + rg2 * 2;
    ushort2v u = *(const ushort2v*)xp;
    xwv[g4][0] = bf2f(u.x); xwv[g4][1] = bf2f(u.y);
  }

  #pragma unroll 1
  for (int t = t0; t < tend; ++t) {
    f32x4 acc[2][2];
    #pragma unroll
    for (int mt = 0; mt < 2; ++mt)
      #pragma unroll
      for (int nt = 0; nt < 2; ++nt) acc[mt][nt] = f32x4{0.f, 0.f, 0.f, 0.f};

    if (t > 0) {
      const unsigned int need = gen_base + 1u + (unsigned int)(t - t0);
      #pragma unroll
      for (int sl = 0; sl < 16; ++sl) {
        const int s = sl >> 2, q = sl & 3;
        int sg = (g + s) & 3;
        if (q == 0 && s > 0) lds_spin(&cflag[kh * 4 + sg], need);
        int cidx = kh * 16 + sg + 4 * q;
        bf16x8 af[2];
        #pragma unroll
        for (int mt = 0; mt < 2; ++mt)
          af[mt] = *(const bf16x8*)((const char*)As + cidx * 2048 + (mt * 16 + l15) * 64 + quad * 16);
        #pragma unroll
        for (int mt = 0; mt < 2; ++mt)
          #pragma unroll
          for (int nt = 0; nt < 2; ++nt)
            acc[mt][nt] = __builtin_amdgcn_mfma_f32_16x16x32_bf16(af[mt], whh[nt][sl], acc[mt][nt], 0, 0, 0);
      }
    }

    #pragma unroll
    for (int mt = 0; mt < 2; ++mt)
      #pragma unroll
      for (int nt = 0; nt < 2; ++nt) {
        int hl = nt * 16 + l15;
        int rq = mt * 16 + quad * 4;
        *(f32x4*)&gbuf[wv][hl][rq] = acc[mt][nt];
      }
    __syncthreads();   // (A)

    unsigned short* hxd = hpp + (size_t)(t & 1) * HXSLOT;
    #pragma unroll
    for (int r = 0; r < 2; ++r) {
      int row = rg2 * 2 + r;
      float gi = gbuf[0][hcl][row] + gbuf[4][hcl][row] + xwv[0][r] + bias[0];
      float gf = gbuf[1][hcl][row] + gbuf[5][hcl][row] + xwv[1][r] + bias[1];
      float gg = gbuf[2][hcl][row] + gbuf[6][hcl][row] + xwv[2][r] + bias[2];
      float go = gbuf[3][hcl][row] + gbuf[7][hcl][row] + xwv[3][r] + bias[3];
      float iv = sigm(gi), fv = sigm(gf), gv = tanh_f(gg), ov = sigm(go);
      float cn = fv * c[r] + iv * gv;
      c[r] = cn;
      float hv = ov * tanh_f(cn);
      unsigned short hb = f2bf(hv);
      hxd[ni * 8192 + (r0 + row) * 32 + hcl] = hb;
      int gidx = (r0 + row) * HDIM + hc0 + hcl;
      if (h1t0 != nullptr && t == 0) h1t0[gidx] = hb;
      if (t == tend - 1) cstate[gidx] = cn;
      if (t == T_STEPS - 1) { dout_h[gidx] = hv; dout_c[gidx] = cn; }
    }
    __syncthreads();   // (B)

    if (t != tend - 1) {
      const unsigned int tgt = gen_base + 2u + (unsigned int)(t - t0);
      if (tid == 0) post_stamp(stamps + ni * 32, tgt, fast);

      // hoisted: xw loads for step t+1
      #pragma unroll
      for (int g4 = 0; g4 < 4; ++g4) {
        const unsigned short* xp =
            xw + ((size_t)(t + 1 - t0) * GDIM + g4 * HDIM + hc0 + hcl) * BATCH + r0 + rg2 * 2;
        ushort2v u = *(const ushort2v*)xp;
        xwv[g4][0] = bf2f(u.x); xwv[g4][1] = bf2f(u.y);
      }

      poll_mine(stamps, g, kh, tgt);
      if (fast) vl1_inv();
      else __builtin_amdgcn_fence(__ATOMIC_ACQUIRE, "agent");
      stage_chunks(hpp + (size_t)(t & 1) * HXSLOT, As, r0, g, kh, lane);
      asm volatile("s_waitcnt vmcnt(0)" ::: "memory");
      if (lane == 0)
        __hip_atomic_store(&cflag[kh * 4 + g], tgt, __ATOMIC_RELEASE, __HIP_MEMORY_SCOPE_WORKGROUP);
    }
  }
}

__global__ void y_kernel(const unsigned short* __restrict__ h1t0,
                         const unsigned short* __restrict__ wlin,
                         const float* __restrict__ blin,
                         float* __restrict__ y)
{
  int b = blockIdx.x;
  int f = threadIdx.x;
  const ushort8v* hp = (const ushort8v*)(h1t0 + (size_t)b * HDIM);
  const ushort8v* wp = (const ushort8v*)(wlin + (size_t)f * HDIM);
  float acc = 0.f;
  for (int i = 0; i < HDIM / 8; ++i) {
    ushort8v hv = hp[i], wvv = wp[i];
    #pragma unroll
    for (int j = 0; j < 8; ++j) acc += bf2f(hv[j]) * bf2f(wvv[j]);
  }
  y[b * FDIM + f] = acc + blin[f];
}

// ---------------------------------------------------------------------------
extern "C" void kernel_launch(void* const* d_in, const int* in_sizes, int n_in,
                              void* d_out, int out_size, void* d_ws, size_t ws_size,
                              hipStream_t stream) {
  (void)in_sizes; (void)n_in; (void)out_size;
  const float* x    = (const float*)d_in[0];
  const float* Wih0 = (const float*)d_in[1];
  const float* Whh0 = (const float*)d_in[2];
  const float* bih0 = (const float*)d_in[3];
  const float* bhh0 = (const float*)d_in[4];
  const float* Wih1 = (const float*)d_in[5];
  const float* Whh1 = (const float*)d_in[6];
  const float* bih1 = (const float*)d_in[7];
  const float* bhh1 = (const float*)d_in[8];
  const float* Wlin = (const float*)d_in[9];
  const float* blin = (const float*)d_in[10];
  float* out = (float*)d_out;

  const size_t SZ_BAR   = 32768;   // 8 groups x 32 stamps x 128B
  const size_t SZ_PROBE = 32768;
  const size_t SZ_XBF   = (size_t)T_STEPS * BATCH * FDIM * 2;
  const size_t SZ_WIH1  = (size_t)GDIM * HDIM * 2;
  const size_t SZ_WLIN  = (size_t)FDIM * HDIM * 2;
  const size_t SZ_HPP   = (size_t)2 * BATCH * HDIM * 2;
  const size_t SZ_HX    = (size_t)2 * BATCH * HDIM * 2;
  const size_t SZ_H1T0  = (size_t)BATCH * HDIM * 2;
  const size_t SZ_CST   = (size_t)BATCH * HDIM * 4;
  const size_t SLOT     = (size_t)BATCH * HDIM * 2;
  const size_t fixed = SZ_BAR + SZ_PROBE + SZ_XBF + SZ_WIH1 + SZ_WLIN + SZ_HPP + SZ_HX + SZ_H1T0 + 2 * SZ_CST;

  int CH = 0;
  const int cands[5] = {64, 32, 16, 8, 4};
  for (int i = 0; i < 5; ++i) {
    int c = cands[i];
    size_t need = fixed + (size_t)(c + 1) * SLOT + (size_t)c * GDIM * BATCH * 2;
    if (need <= ws_size) { CH = c; break; }
  }
  if (CH == 0) {
    float v = 1.0e6f + (float)(ws_size >> 20);
    diag_kernel<<<(32768 + 255) / 256, 256, 0, stream>>>(out, 32768, v);
    return;
  }

  char* ws = (char*)d_ws;
  size_t o = 0;
  unsigned int*   bar   = (unsigned int*)(ws + o);    o += SZ_BAR;
  unsigned int*   probe = (unsigned int*)(ws + o);    o += SZ_PROBE;
  unsigned short* xbf   = (unsigned short*)(ws + o);  o += SZ_XBF;
  unsigned short* wih1b = (unsigned short*)(ws + o);  o += SZ_WIH1;
  unsigned short* wlinb = (unsigned short*)(ws + o);  o += SZ_WLIN;
  unsigned short* h1pp  = (unsigned short*)(ws + o);  o += SZ_HPP;
  unsigned short* hx0   = (unsigned short*)(ws + o);  o += SZ_HX;
  unsigned short* h1t0  = (unsigned short*)(ws + o);  o += SZ_H1T0;
  float*          c0st  = (float*)(ws + o);           o += SZ_CST;
  float*          c1st  = (float*)(ws + o);           o += SZ_CST;
  unsigned short* slab  = (unsigned short*)(ws + o);  o += (size_t)(CH + 1) * SLOT;
  unsigned short* xw1   = (unsigned short*)(ws + o);  o += (size_t)CH * GDIM * BATCH * 2;

  hipMemsetAsync(bar, 0, SZ_BAR, stream);

  conv_bf16<<<(T_STEPS * BATCH * FDIM + 255) / 256, 256, 0, stream>>>(x, xbf, T_STEPS * BATCH * FDIM);
  conv_bf16<<<(GDIM * HDIM + 255) / 256, 256, 0, stream>>>(Wih1, wih1b, GDIM * HDIM);
  conv_bf16<<<(FDIM * HDIM + 255) / 256, 256, 0, stream>>>(Wlin, wlinb, FDIM * HDIM);

  float* hn0 = out + 32768;
  float* hn1 = out + 32768 + 262144;
  float* cn0 = out + 32768 + 524288;
  float* cn1 = out + 32768 + 524288 + 262144;

  unsigned int gen_base = 0;
  for (int ch = 0; ch < T_STEPS / CH; ++ch) {
    int t0 = ch * CH;
    lstm_layer0_kernel<<<256, 512, 0, stream>>>(
        xbf, Wih0, Whh0, bih0, bhh0, slab, hx0, c0st, t0, CH, gen_base, hn0, cn0, bar, probe);
    gen_base += (unsigned int)CH;   // 1 probe + (CH-1) step stamps
    gemm_bt_xw<<<dim3(CH * 2, 32), 256, 0, stream>>>(
        slab + BATCH * HDIM, wih1b, xw1, HDIM);
    lstm_layer1_kernel<<<256, 512, 0, stream>>>(
        xw1, Whh1, bih1, bhh1, h1pp, c1st, t0, CH, gen_base, h1t0, hn1, cn1, bar, probe);
    gen_base += (unsigned int)CH;
  }

  y_kernel<<<256, 128, 0, stream>>>(h1t0, wlinb, blin, out);
}

// Round 7
// 3548.227 us; speedup vs baseline: 1.0212x; 1.0212x over previous
//
#include <hip/hip_runtime.h>
#include <stdint.h>

// ---------------------------------------------------------------------------
// 2-layer LSTM (T=256, B=256, F=128, H=1024) for MI355X (gfx950).
// R13: conflict-fix + overhead trims on the R12 structure (three sync designs
// all measured 5.6-6.0us/step -> chain-latency-bound; this round is a clean
// LDS-conflict experiment + dispatch-count reduction).
//   (1) As chunk XOR-swizzle, both-sides (rule #21): producer h-stores into
//       hx/hpp apply b ^= ((b>>7)&3)<<4 within each 2KB sub-block; staging
//       stays a LINEAR global_load_lds copy; MFMA reads apply the same XOR.
//       Read granule (4rr+quad)^((rr>>1)&3) mod 8 covers all 8 bank groups:
//       8-way -> 2-way (free). Mask bits 7-8 disjoint from flipped bits 4-5
//       -> involution; stores stay in-line -> coalescing unchanged.
//   (2) gbuf [8][32][36] -> [8][32][33], scalar writes: EW reads 4-way -> 0
//       (33*hcl mod 32 = hcl), writes <=2-way. -3KB LDS.
//   (3) CH candidates {256,128,64,...}: fewer dispatches (probe + weight
//       reload + launch overhead) if workspace permits.
//   (4) poll busy-spin lengthened before s_sleep (detect latency).
// Everything else identical to R12 (chunk flags, stamps, probe, fast/heavy).
// ---------------------------------------------------------------------------

typedef __bf16 bf16x8 __attribute__((ext_vector_type(8)));
typedef float  f32x4  __attribute__((ext_vector_type(4)));
typedef unsigned short ushort8v __attribute__((ext_vector_type(8)));
typedef unsigned short ushort4v __attribute__((ext_vector_type(4)));
typedef unsigned short ushort2v __attribute__((ext_vector_type(2)));
typedef __attribute__((address_space(1))) unsigned int as1_u32;
typedef __attribute__((address_space(3))) unsigned int as3_u32;

#define T_STEPS 256
#define BATCH   256
#define HDIM    1024
#define GDIM    4096
#define FDIM    128
#define HXSLOT  (BATCH * HDIM)   // elements per blocked h slot (512KB)

static __device__ __forceinline__ float bf2f(unsigned short u) {
  union { unsigned int i; float f; } v; v.i = ((unsigned int)u) << 16; return v.f;
}
static __device__ __forceinline__ unsigned short f2bf(float f) {
  return __builtin_bit_cast(unsigned short, (__bf16)f);
}
static __device__ __forceinline__ float sigm(float x) { return 1.f / (1.f + __expf(-x)); }
static __device__ __forceinline__ float tanh_f(float x) { return 2.f / (1.f + __expf(-2.f * x)) - 1.f; }

// 2KB-sub-block bank swizzle (involution): flips byte bits 4-5 by row-pair.
static __device__ __forceinline__ int swz(int b) {
  return b ^ (((b >> 7) & 3) << 4);
}

static __device__ __forceinline__ void vl1_inv() {
  asm volatile("buffer_inv" ::: "memory");
}

__global__ void conv_bf16(const float* __restrict__ s, unsigned short* __restrict__ d, int n) {
  int i = blockIdx.x * 256 + threadIdx.x;
  if (i < n) d[i] = f2bf(s[i]);
}

__global__ void diag_kernel(float* out, int n, float v) {
  int i = blockIdx.x * 256 + threadIdx.x;
  if (i < n) out[i] = v;
}

// ------------------------- stamps / polls / flags ----------------------------
__device__ __forceinline__ void post_stamp(unsigned int* st, unsigned int gen, bool fast) {
  if (!fast) __builtin_amdgcn_fence(__ATOMIC_RELEASE, "agent");
  __hip_atomic_store(st, gen, __ATOMIC_RELAXED, __HIP_MEMORY_SCOPE_AGENT);
}

__device__ __forceinline__ void poll_all(unsigned int* stamps, unsigned int target) {
  unsigned int* p = stamps + (threadIdx.x & 31) * 32;
  for (unsigned int it = 0; it < (1u << 15); ++it) {
    unsigned int gv = __hip_atomic_load(p, __ATOMIC_RELAXED, __HIP_MEMORY_SCOPE_AGENT);
    if (__all((int)(gv - target) >= 0)) return;
    if (it > 16) __builtin_amdgcn_s_sleep(1);
  }
}

__device__ __forceinline__ void poll_mine(unsigned int* stamps, int g, int kh, unsigned int target) {
  unsigned int* p = stamps + (kh * 16 + g + 4 * ((int)threadIdx.x & 3)) * 32;
  for (unsigned int it = 0; it < (1u << 15); ++it) {
    unsigned int gv = __hip_atomic_load(p, __ATOMIC_RELAXED, __HIP_MEMORY_SCOPE_AGENT);
    if (__all((int)(gv - target) >= 0)) return;
    if (it > 64) __builtin_amdgcn_s_sleep(1);
  }
}

__device__ __forceinline__ void lds_spin(unsigned int* f, unsigned int need) {
  for (unsigned int it = 0; it < (1u << 15); ++it) {
    unsigned int v = __hip_atomic_load(f, __ATOMIC_ACQUIRE, __HIP_MEMORY_SCOPE_WORKGROUP);
    if ((int)(v - need) >= 0) return;
    if (it > 32) __builtin_amdgcn_s_sleep(1);
  }
}

// Stage this wave's 4 chunks (2KB each, contiguous in blocked h) into
// chunk-major As via global_load_lds width-16 (linear copy; the bank
// swizzle is baked into the producer's store addresses).
__device__ __forceinline__ void stage_chunks(const unsigned short* __restrict__ hsrc,
                                             unsigned short* AsPtr, int r0, int g, int kh, int lane) {
  #pragma unroll
  for (int q = 0; q < 4; ++q) {
    int c = kh * 16 + g + 4 * q;
    const char* src = (const char*)(hsrc + (size_t)c * 8192 + r0 * 32);
    char* dst = (char*)AsPtr + c * 2048;
    __builtin_amdgcn_global_load_lds((const as1_u32*)(src + lane * 16), (as3_u32*)dst, 16, 0, 0);
    __builtin_amdgcn_global_load_lds((const as1_u32*)(src + 1024 + lane * 16), (as3_u32*)(dst + 1024), 16, 0, 0);
  }
}

// --------------------------- gemm_bt: C = A @ B^T ---------------------------
__global__ __launch_bounds__(256) void gemm_bt_xw(
    const unsigned short* __restrict__ A,
    const unsigned short* __restrict__ B,
    unsigned short* __restrict__ xw,
    int K)
{
  const int tid = threadIdx.x, lane = tid & 63, w = tid >> 6;
  const int m0 = blockIdx.x * 128;
  const int n0 = blockIdx.y * 128;
  __shared__ unsigned short As[128 * 64];
  __shared__ unsigned short Bs[128 * 64];
  const int mrow0 = (w & 1) * 64, ncol0 = (w >> 1) * 64;
  const int quad = lane >> 4;

  f32x4 acc[4][4];
  #pragma unroll
  for (int i = 0; i < 4; ++i)
    #pragma unroll
    for (int j = 0; j < 4; ++j) acc[i][j] = f32x4{0.f, 0.f, 0.f, 0.f};

  const int kiter = K >> 6;
  for (int ki = 0; ki < kiter; ++ki) {
    const int k0 = ki * 64;
    __syncthreads();
    #pragma unroll
    for (int i = 0; i < 4; ++i) {
      int obase = (w * 4 + i) * 1024;          // wave-uniform LDS byte base
      int o = obase + lane * 16;
      int row = o >> 7; int kb = o & 127;
      const char* ga = (const char*)A + ((size_t)(m0 + row) * K + k0) * 2 + kb;
      const char* gb = (const char*)B + ((size_t)(n0 + row) * K + k0) * 2 + kb;
      __builtin_amdgcn_global_load_lds((const as1_u32*)ga, (as3_u32*)((char*)As + obase), 16, 0, 0);
      __builtin_amdgcn_global_load_lds((const as1_u32*)gb, (as3_u32*)((char*)Bs + obase), 16, 0, 0);
    }
    __syncthreads();
    #pragma unroll
    for (int kk = 0; kk < 2; ++kk) {
      bf16x8 af[4], bfr[4];
      #pragma unroll
      for (int mt = 0; mt < 4; ++mt)
        af[mt] = *(const bf16x8*)(As + (mrow0 + mt * 16 + (lane & 15)) * 64 + kk * 32 + quad * 8);
      #pragma unroll
      for (int nt = 0; nt < 4; ++nt)
        bfr[nt] = *(const bf16x8*)(Bs + (ncol0 + nt * 16 + (lane & 15)) * 64 + kk * 32 + quad * 8);
      #pragma unroll
      for (int mt = 0; mt < 4; ++mt)
        #pragma unroll
        for (int nt = 0; nt < 4; ++nt)
          acc[mt][nt] = __builtin_amdgcn_mfma_f32_16x16x32_bf16(af[mt], bfr[nt], acc[mt][nt], 0, 0, 0);
    }
  }
  #pragma unroll
  for (int mt = 0; mt < 4; ++mt) {
    int m = m0 + mrow0 + mt * 16 + quad * 4;
    int tl = m >> 8, b = m & 255;
    #pragma unroll
    for (int nt = 0; nt < 4; ++nt) {
      int col = n0 + ncol0 + nt * 16 + (lane & 15);
      ushort4v v;
      v.x = f2bf(acc[mt][nt][0]); v.y = f2bf(acc[mt][nt][1]);
      v.z = f2bf(acc[mt][nt][2]); v.w = f2bf(acc[mt][nt][3]);
      *(ushort4v*)(xw + ((size_t)tl * GDIM + col) * BATCH + b) = v;
    }
  }
}

// ---------------- probe: validate intra-XCD visibility for this group --------
__device__ __forceinline__ bool probe_chk(unsigned int* probeBuf, unsigned int* stamps,
                                          unsigned int salt, unsigned int target,
                                          unsigned int* flagLds) {
  const int wg = blockIdx.x, mi = wg & 7, ni = wg >> 3;
  const int tid = threadIdx.x;
  if (tid == 0) probeBuf[wg * 32] = salt ^ (unsigned int)wg;
  __syncthreads();   // drains token store to L2
  if (tid == 0)
    __hip_atomic_store(stamps + ni * 32, target, __ATOMIC_RELAXED, __HIP_MEMORY_SCOPE_AGENT);
  poll_all(stamps, target);
  vl1_inv();
  if (tid == 0) {
    unsigned int bad = 0;
    for (int k = 0; k < 32; ++k) {
      int member = mi + 8 * k;
      unsigned int v = probeBuf[member * 32];
      if (v != (salt ^ (unsigned int)member)) bad = 1;
    }
    *flagLds = bad;
  }
  __syncthreads();
  return (*flagLds == 0);
}

// --------------------------- layer 0: fused persistent chunk -----------------
// 256 WGs x 512 thr, 1/CU. WG (mi=wg&7, ni=wg>>3): rows [32mi,+32), cols [32ni,+32).
// Wave wv: gate g=wv&3, K-half kh=wv>>2. whh[2][16] slots in CONSUME order.
__global__ __launch_bounds__(512, 2) void lstm_layer0_kernel(
    const unsigned short* __restrict__ xbf,  // (T,B,F) bf16
    const float* __restrict__ Wih,           // (4096,128) fp32
    const float* __restrict__ Whh,           // (4096,1024) fp32
    const float* __restrict__ bih,
    const float* __restrict__ bhh,
    unsigned short* __restrict__ slab,       // (ch_len+1, B, H) bf16 row-major, gemm feed
    unsigned short* __restrict__ hx,         // 2-slot blocked+swizzled ping-pong
    float* __restrict__ cstate,              // (B,H) fp32
    int t0, int ch_len, unsigned int gen_base,
    float* __restrict__ dout_h,
    float* __restrict__ dout_c,
    unsigned int* __restrict__ bar,
    unsigned int* __restrict__ probe)
{
  const int tid = threadIdx.x, lane = tid & 63, wv = tid >> 6;   // wv 0..7
  const int quad = lane >> 4, l15 = lane & 15;
  const int g = wv & 3, kh = wv >> 2;
  const int wg = blockIdx.x;
  const int mi = wg & 7, ni = wg >> 3;
  const int r0 = mi * 32, hc0 = ni * 32;
  unsigned int* stamps = bar + mi * 1024;

  __shared__ unsigned short As[32 * 1024];   // chunk-major: [32 chunks][2KB swizzled]
  __shared__ float gbuf[8][32][33];          // 33: EW reads conflict-free
  __shared__ unsigned int cflag[8];          // per-(kh,g) stager flags
  __shared__ unsigned int flagLds;

  if (tid < 8) cflag[tid] = 0;

  // W_hh fragment, slots permuted into consume order:
  // slot sl -> chunk j(sl) = ((g + (sl>>2)) & 3) + 4*(sl&3)
  bf16x8 whh[2][16];
  #pragma unroll
  for (int nt = 0; nt < 2; ++nt) {
    #pragma unroll
    for (int sl = 0; sl < 16; ++sl) {
      int jj = ((g + (sl >> 2)) & 3) + 4 * (sl & 3);
      const float* wrow = Whh + (size_t)(g * HDIM + hc0 + nt * 16 + l15) * HDIM + kh * 512 + jj * 32 + quad * 8;
      f32x4 f0 = *(const f32x4*)(wrow);
      f32x4 f1 = *(const f32x4*)(wrow + 4);
      bf16x8 r;
      r[0] = (__bf16)f0[0]; r[1] = (__bf16)f0[1]; r[2] = (__bf16)f0[2]; r[3] = (__bf16)f0[3];
      r[4] = (__bf16)f1[0]; r[5] = (__bf16)f1[1]; r[6] = (__bf16)f1[2]; r[7] = (__bf16)f1[3];
      whh[nt][sl] = r;
    }
  }
  // W_ih fragment: K=128 split across kh (64 each)
  bf16x8 wih[2][2];
  #pragma unroll
  for (int nt = 0; nt < 2; ++nt) {
    const float* wrow = Wih + (size_t)(g * HDIM + hc0 + nt * 16 + l15) * FDIM + kh * 64 + quad * 8;
    #pragma unroll
    for (int kk = 0; kk < 2; ++kk) {
      f32x4 f0 = *(const f32x4*)(wrow + kk * 32);
      f32x4 f1 = *(const f32x4*)(wrow + kk * 32 + 4);
      bf16x8 r;
      r[0] = (__bf16)f0[0]; r[1] = (__bf16)f0[1]; r[2] = (__bf16)f0[2]; r[3] = (__bf16)f0[3];
      r[4] = (__bf16)f1[0]; r[5] = (__bf16)f1[1]; r[6] = (__bf16)f1[2]; r[7] = (__bf16)f1[3];
      wih[nt][kk] = r;
    }
  }

  const int hcl = tid & 31, rg2 = tid >> 5;
  float bias[4];
  #pragma unroll
  for (int b4 = 0; b4 < 4; ++b4)
    bias[b4] = bih[b4 * HDIM + hc0 + hcl] + bhh[b4 * HDIM + hc0 + hcl];

  float c[2];
  #pragma unroll
  for (int r = 0; r < 2; ++r)
    c[r] = (t0 == 0) ? 0.f : cstate[(size_t)(r0 + rg2 * 2 + r) * HDIM + hc0 + hcl];

  unsigned int salt = 0x9E3779B9u ^ (gen_base * 2654435761u);
  bool fast = probe_chk(probe, stamps, salt, gen_base + 1u, &flagLds);

  const int tend = t0 + ch_len;

  // prologue: cross-kernel h stage (blocked+swizzled hx from prev dispatch)
  if (t0 > 0) {
    stage_chunks(hx + (size_t)((t0 - 1) & 1) * HXSLOT, As, r0, g, kh, lane);
    asm volatile("s_waitcnt vmcnt(0)" ::: "memory");
    if (lane == 0)
      __hip_atomic_store(&cflag[kh * 4 + g], gen_base + 1u, __ATOMIC_RELEASE, __HIP_MEMORY_SCOPE_WORKGROUP);
  }

  // prologue: x-projection for the first step
  f32x4 acc[2][2];
  #pragma unroll
  for (int mt = 0; mt < 2; ++mt)
    #pragma unroll
    for (int nt = 0; nt < 2; ++nt) acc[mt][nt] = f32x4{0.f, 0.f, 0.f, 0.f};
  #pragma unroll
  for (int j = 0; j < 2; ++j) {
    bf16x8 af[2];
    #pragma unroll
    for (int mt = 0; mt < 2; ++mt)
      af[mt] = *(const bf16x8*)(xbf + (size_t)(t0 * BATCH + r0 + mt * 16 + l15) * FDIM + kh * 64 + j * 32 + quad * 8);
    #pragma unroll
    for (int mt = 0; mt < 2; ++mt)
      #pragma unroll
      for (int nt = 0; nt < 2; ++nt)
        acc[mt][nt] = __builtin_amdgcn_mfma_f32_16x16x32_bf16(af[mt], wih[nt][j], acc[mt][nt], 0, 0, 0);
  }

  #pragma unroll 1
  for (int t = t0; t < tend; ++t) {
    if (t > 0) {
      // consume 16 chunks in 4 stager-batches; self batch needs no spin.
      const unsigned int need = gen_base + 1u + (unsigned int)(t - t0);
      #pragma unroll
      for (int sl = 0; sl < 16; ++sl) {
        const int s = sl >> 2, q = sl & 3;
        int sg = (g + s) & 3;
        if (q == 0 && s > 0) lds_spin(&cflag[kh * 4 + sg], need);
        int cidx = kh * 16 + sg + 4 * q;
        bf16x8 af[2];
        #pragma unroll
        for (int mt = 0; mt < 2; ++mt) {
          int bo = (mt * 16 + l15) * 64 + quad * 16;
          bo = swz(bo);
          af[mt] = *(const bf16x8*)((const char*)As + cidx * 2048 + bo);
        }
        #pragma unroll
        for (int mt = 0; mt < 2; ++mt)
          #pragma unroll
          for (int nt = 0; nt < 2; ++nt)
            acc[mt][nt] = __builtin_amdgcn_mfma_f32_16x16x32_bf16(af[mt], whh[nt][sl], acc[mt][nt], 0, 0, 0);
      }
    }

    #pragma unroll
    for (int mt = 0; mt < 2; ++mt)
      #pragma unroll
      for (int nt = 0; nt < 2; ++nt) {
        int hl = nt * 16 + l15;
        int rq = mt * 16 + quad * 4;
        #pragma unroll
        for (int i = 0; i < 4; ++i)
          gbuf[wv][hl][rq + i] = acc[mt][nt][i];   // scalar: <=2-way at 33
      }
    __syncthreads();   // (A) gbuf visible; all As reads of step t complete

    unsigned short* hdst = slab + (size_t)(t - t0 + 1) * (BATCH * HDIM);
    unsigned short* hxd  = hx + (size_t)(t & 1) * HXSLOT;
    #pragma unroll
    for (int r = 0; r < 2; ++r) {
      int row = rg2 * 2 + r;
      float gi = gbuf[0][hcl][row] + gbuf[4][hcl][row] + bias[0];
      float gf = gbuf[1][hcl][row] + gbuf[5][hcl][row] + bias[1];
      float gg = gbuf[2][hcl][row] + gbuf[6][hcl][row] + bias[2];
      float go = gbuf[3][hcl][row] + gbuf[7][hcl][row] + bias[3];
      float iv = sigm(gi), fv = sigm(gf), gv = tanh_f(gg), ov = sigm(go);
      float cn = fv * c[r] + iv * gv;
      c[r] = cn;
      float hv = ov * tanh_f(cn);
      unsigned short hb = f2bf(hv);
      // blocked+swizzled hx: chunk ni, sub-block mi, swizzled byte offset
      int boff = swz(row * 64 + hcl * 2);
      hxd[ni * 8192 + mi * 1024 + (boff >> 1)] = hb;
      int gidx = (r0 + row) * HDIM + hc0 + hcl;
      hdst[gidx] = hb;       // gemm feed (row-major, unswizzled)
      if (t == tend - 1) cstate[gidx] = cn;
      if (t == T_STEPS - 1) { dout_h[gidx] = hv; dout_c[gidx] = cn; }
    }
    __syncthreads();   // (B) drains h stores (vmcnt 0) -> visible at L2

    if (t != tend - 1) {
      const unsigned int tgt = gen_base + 2u + (unsigned int)(t - t0);
      if (tid == 0) post_stamp(stamps + ni * 32, tgt, fast);

      // hoisted: x-projection for step t+1 (independent of h(t))
      #pragma unroll
      for (int mt = 0; mt < 2; ++mt)
        #pragma unroll
        for (int nt = 0; nt < 2; ++nt) acc[mt][nt] = f32x4{0.f, 0.f, 0.f, 0.f};
      #pragma unroll
      for (int j = 0; j < 2; ++j) {
        bf16x8 af[2];
        #pragma unroll
        for (int mt = 0; mt < 2; ++mt)
          af[mt] = *(const bf16x8*)(xbf + (size_t)((t + 1) * BATCH + r0 + mt * 16 + l15) * FDIM + kh * 64 + j * 32 + quad * 8);
        #pragma unroll
        for (int mt = 0; mt < 2; ++mt)
          #pragma unroll
          for (int nt = 0; nt < 2; ++nt)
            acc[mt][nt] = __builtin_amdgcn_mfma_f32_16x16x32_bf16(af[mt], wih[nt][j], acc[mt][nt], 0, 0, 0);
      }

      // exchange: wait only for MY 4 producers, stage my chunks, flag.
      poll_mine(stamps, g, kh, tgt);
      if (fast) vl1_inv();
      else __builtin_amdgcn_fence(__ATOMIC_ACQUIRE, "agent");
      stage_chunks(hx + (size_t)(t & 1) * HXSLOT, As, r0, g, kh, lane);
      asm volatile("s_waitcnt vmcnt(0)" ::: "memory");
      if (lane == 0)
        __hip_atomic_store(&cflag[kh * 4 + g], tgt, __ATOMIC_RELEASE, __HIP_MEMORY_SCOPE_WORKGROUP);
    }
  }
}

// --------------------------- layer 1: persistent chunk ----------------------
__global__ __launch_bounds__(512, 2) void lstm_layer1_kernel(
    const unsigned short* __restrict__ xw,   // (ch_len, 4096, 256) bf16
    const float* __restrict__ Whh,
    const float* __restrict__ bih,
    const float* __restrict__ bhh,
    unsigned short* __restrict__ hpp,        // 2-slot blocked+swizzled ping-pong
    float* __restrict__ cstate,
    int t0, int ch_len, unsigned int gen_base,
    unsigned short* __restrict__ h1t0,
    float* __restrict__ dout_h,
    float* __restrict__ dout_c,
    unsigned int* __restrict__ bar,
    unsigned int* __restrict__ probe)
{
  const int tid = threadIdx.x, lane = tid & 63, wv = tid >> 6;
  const int quad = lane >> 4, l15 = lane & 15;
  const int g = wv & 3, kh = wv >> 2;
  const int wg = blockIdx.x;
  const int mi = wg & 7, ni = wg >> 3;
  const int r0 = mi * 32, hc0 = ni * 32;
  unsigned int* stamps = bar + mi * 1024;

  __shared__ unsigned short As[32 * 1024];
  __shared__ float gbuf[8][32][33];
  __shared__ unsigned int cflag[8];
  __shared__ unsigned int flagLds;

  if (tid < 8) cflag[tid] = 0;

  bf16x8 whh[2][16];
  #pragma unroll
  for (int nt = 0; nt < 2; ++nt) {
    #pragma unroll
    for (int sl = 0; sl < 16; ++sl) {
      int jj = ((g + (sl >> 2)) & 3) + 4 * (sl & 3);
      const float* wrow = Whh + (size_t)(g * HDIM + hc0 + nt * 16 + l15) * HDIM + kh * 512 + jj * 32 + quad * 8;
      f32x4 f0 = *(const f32x4*)(wrow);
      f32x4 f1 = *(const f32x4*)(wrow + 4);
      bf16x8 r;
      r[0] = (__bf16)f0[0]; r[1] = (__bf16)f0[1]; r[2] = (__bf16)f0[2]; r[3] = (__bf16)f0[3];
      r[4] = (__bf16)f1[0]; r[5] = (__bf16)f1[1]; r[6] = (__bf16)f1[2]; r[7] = (__bf16)f1[3];
      whh[nt][sl] = r;
    }
  }

  const int hcl = tid & 31, rg2 = tid >> 5;
  float bias[4];
  #pragma unroll
  for (int b4 = 0; b4 < 4; ++b4)
    bias[b4] = bih[b4 * HDIM + hc0 + hcl] + bhh[b4 * HDIM + hc0 + hcl];

  float c[2];
  #pragma unroll
  for (int r = 0; r < 2; ++r)
    c[r] = (t0 == 0) ? 0.f : cstate[(size_t)(r0 + rg2 * 2 + r) * HDIM + hc0 + hcl];

  unsigned int salt = 0xB5297A4Du ^ (gen_base * 2654435761u);
  bool fast = probe_chk(probe, stamps, salt, gen_base + 1u, &flagLds);

  const int tend = t0 + ch_len;

  if (t0 > 0) {
    stage_chunks(hpp + (size_t)((t0 - 1) & 1) * HXSLOT, As, r0, g, kh, lane);
    asm volatile("s_waitcnt vmcnt(0)" ::: "memory");
    if (lane == 0)
      __hip_atomic_store(&cflag[kh * 4 + g], gen_base + 1u, __ATOMIC_RELEASE, __HIP_MEMORY_SCOPE_WORKGROUP);
  }

  float xwv[4][2];
  #pragma unroll
  for (int g4 = 0; g4 < 4; ++g4) {
    const unsigned short* xp =
        xw + ((size_t)0 * GDIM + g4 * HDIM + hc0 + hcl) * BATCH + r0 + rg2 * 2;
    ushort2v u = *(const ushort2v*)xp;
    xwv[g4][0] = bf2f(u.x); xwv[g4][1] = bf2f(u.y);
  }

  #pragma unroll 1
  for (int t = t0; t < tend; ++t) {
    f32x4 acc[2][2];
    #pragma unroll
    for (int mt = 0; mt < 2; ++mt)
      #pragma unroll
      for (int nt = 0; nt < 2; ++nt) acc[mt][nt] = f32x4{0.f, 0.f, 0.f, 0.f};

    if (t > 0) {
      const unsigned int need = gen_base + 1u + (unsigned int)(t - t0);
      #pragma unroll
      for (int sl = 0; sl < 16; ++sl) {
        const int s = sl >> 2, q = sl & 3;
        int sg = (g + s) & 3;
        if (q == 0 && s > 0) lds_spin(&cflag[kh * 4 + sg], need);
        int cidx = kh * 16 + sg + 4 * q;
        bf16x8 af[2];
        #pragma unroll
        for (int mt = 0; mt < 2; ++mt) {
          int bo = (mt * 16 + l15) * 64 + quad * 16;
          bo = swz(bo);
          af[mt] = *(const bf16x8*)((const char*)As + cidx * 2048 + bo);
        }
        #pragma unroll
        for (int mt = 0; mt < 2; ++mt)
          #pragma unroll
          for (int nt = 0; nt < 2; ++nt)
            acc[mt][nt] = __builtin_amdgcn_mfma_f32_16x16x32_bf16(af[mt], whh[nt][sl], acc[mt][nt], 0, 0, 0);
      }
    }

    #pragma unroll
    for (int mt = 0; mt < 2; ++mt)
      #pragma unroll
      for (int nt = 0; nt < 2; ++nt) {
        int hl = nt * 16 + l15;
        int rq = mt * 16 + quad * 4;
        #pragma unroll
        for (int i = 0; i < 4; ++i)
          gbuf[wv][hl][rq + i] = acc[mt][nt][i];
      }
    __syncthreads();   // (A)

    unsigned short* hxd = hpp + (size_t)(t & 1) * HXSLOT;
    #pragma unroll
    for (int r = 0; r < 2; ++r) {
      int row = rg2 * 2 + r;
      float gi = gbuf[0][hcl][row] + gbuf[4][hcl][row] + xwv[0][r] + bias[0];
      float gf = gbuf[1][hcl][row] + gbuf[5][hcl][row] + xwv[1][r] + bias[1];
      float gg = gbuf[2][hcl][row] + gbuf[6][hcl][row] + xwv[2][r] + bias[2];
      float go = gbuf[3][hcl][row] + gbuf[7][hcl][row] + xwv[3][r] + bias[3];
      float iv = sigm(gi), fv = sigm(gf), gv = tanh_f(gg), ov = sigm(go);
      float cn = fv * c[r] + iv * gv;
      c[r] = cn;
      float hv = ov * tanh_f(cn);
      unsigned short hb = f2bf(hv);
      int boff = swz(row * 64 + hcl * 2);
      hxd[ni * 8192 + mi * 1024 + (boff >> 1)] = hb;
      int gidx = (r0 + row) * HDIM + hc0 + hcl;
      if (h1t0 != nullptr && t == 0) h1t0[gidx] = hb;
      if (t == tend - 1) cstate[gidx] = cn;
      if (t == T_STEPS - 1) { dout_h[gidx] = hv; dout_c[gidx] = cn; }
    }
    __syncthreads();   // (B)

    if (t != tend - 1) {
      const unsigned int tgt = gen_base + 2u + (unsigned int)(t - t0);
      if (tid == 0) post_stamp(stamps + ni * 32, tgt, fast);

      // hoisted: xw loads for step t+1
      #pragma unroll
      for (int g4 = 0; g4 < 4; ++g4) {
        const unsigned short* xp =
            xw + ((size_t)(t + 1 - t0) * GDIM + g4 * HDIM + hc0 + hcl) * BATCH + r0 + rg2 * 2;
        ushort2v u = *(const ushort2v*)xp;
        xwv[g4][0] = bf2f(u.x); xwv[g4][1] = bf2f(u.y);
      }

      poll_mine(stamps, g, kh, tgt);
      if (fast) vl1_inv();
      else __builtin_amdgcn_fence(__ATOMIC_ACQUIRE, "agent");
      stage_chunks(hpp + (size_t)(t & 1) * HXSLOT, As, r0, g, kh, lane);
      asm volatile("s_waitcnt vmcnt(0)" ::: "memory");
      if (lane == 0)
        __hip_atomic_store(&cflag[kh * 4 + g], tgt, __ATOMIC_RELEASE, __HIP_MEMORY_SCOPE_WORKGROUP);
    }
  }
}

__global__ void y_kernel(const unsigned short* __restrict__ h1t0,
                         const unsigned short* __restrict__ wlin,
                         const float* __restrict__ blin,
                         float* __restrict__ y)
{
  int b = blockIdx.x;
  int f = threadIdx.x;
  const ushort8v* hp = (const ushort8v*)(h1t0 + (size_t)b * HDIM);
  const ushort8v* wp = (const ushort8v*)(wlin + (size_t)f * HDIM);
  float acc = 0.f;
  for (int i = 0; i < HDIM / 8; ++i) {
    ushort8v hv = hp[i], wvv = wp[i];
    #pragma unroll
    for (int j = 0; j < 8; ++j) acc += bf2f(hv[j]) * bf2f(wvv[j]);
  }
  y[b * FDIM + f] = acc + blin[f];
}

// ---------------------------------------------------------------------------
extern "C" void kernel_launch(void* const* d_in, const int* in_sizes, int n_in,
                              void* d_out, int out_size, void* d_ws, size_t ws_size,
                              hipStream_t stream) {
  (void)in_sizes; (void)n_in; (void)out_size;
  const float* x    = (const float*)d_in[0];
  const float* Wih0 = (const float*)d_in[1];
  const float* Whh0 = (const float*)d_in[2];
  const float* bih0 = (const float*)d_in[3];
  const float* bhh0 = (const float*)d_in[4];
  const float* Wih1 = (const float*)d_in[5];
  const float* Whh1 = (const float*)d_in[6];
  const float* bih1 = (const float*)d_in[7];
  const float* bhh1 = (const float*)d_in[8];
  const float* Wlin = (const float*)d_in[9];
  const float* blin = (const float*)d_in[10];
  float* out = (float*)d_out;

  const size_t SZ_BAR   = 32768;   // 8 groups x 32 stamps x 128B
  const size_t SZ_PROBE = 32768;
  const size_t SZ_XBF   = (size_t)T_STEPS * BATCH * FDIM * 2;
  const size_t SZ_WIH1  = (size_t)GDIM * HDIM * 2;
  const size_t SZ_WLIN  = (size_t)FDIM * HDIM * 2;
  const size_t SZ_HPP   = (size_t)2 * BATCH * HDIM * 2;
  const size_t SZ_HX    = (size_t)2 * BATCH * HDIM * 2;
  const size_t SZ_H1T0  = (size_t)BATCH * HDIM * 2;
  const size_t SZ_CST   = (size_t)BATCH * HDIM * 4;
  const size_t SLOT     = (size_t)BATCH * HDIM * 2;
  const size_t fixed = SZ_BAR + SZ_PROBE + SZ_XBF + SZ_WIH1 + SZ_WLIN + SZ_HPP + SZ_HX + SZ_H1T0 + 2 * SZ_CST;

  int CH = 0;
  const int cands[7] = {256, 128, 64, 32, 16, 8, 4};
  for (int i = 0; i < 7; ++i) {
    int c = cands[i];
    size_t need = fixed + (size_t)(c + 1) * SLOT + (size_t)c * GDIM * BATCH * 2;
    if (need <= ws_size) { CH = c; break; }
  }
  if (CH == 0) {
    float v = 1.0e6f + (float)(ws_size >> 20);
    diag_kernel<<<(32768 + 255) / 256, 256, 0, stream>>>(out, 32768, v);
    return;
  }

  char* ws = (char*)d_ws;
  size_t o = 0;
  unsigned int*   bar   = (unsigned int*)(ws + o);    o += SZ_BAR;
  unsigned int*   probe = (unsigned int*)(ws + o);    o += SZ_PROBE;
  unsigned short* xbf   = (unsigned short*)(ws + o);  o += SZ_XBF;
  unsigned short* wih1b = (unsigned short*)(ws + o);  o += SZ_WIH1;
  unsigned short* wlinb = (unsigned short*)(ws + o);  o += SZ_WLIN;
  unsigned short* h1pp  = (unsigned short*)(ws + o);  o += SZ_HPP;
  unsigned short* hx0   = (unsigned short*)(ws + o);  o += SZ_HX;
  unsigned short* h1t0  = (unsigned short*)(ws + o);  o += SZ_H1T0;
  float*          c0st  = (float*)(ws + o);           o += SZ_CST;
  float*          c1st  = (float*)(ws + o);           o += SZ_CST;
  unsigned short* slab  = (unsigned short*)(ws + o);  o += (size_t)(CH + 1) * SLOT;
  unsigned short* xw1   = (unsigned short*)(ws + o);  o += (size_t)CH * GDIM * BATCH * 2;

  hipMemsetAsync(bar, 0, SZ_BAR, stream);

  conv_bf16<<<(T_STEPS * BATCH * FDIM + 255) / 256, 256, 0, stream>>>(x, xbf, T_STEPS * BATCH * FDIM);
  conv_bf16<<<(GDIM * HDIM + 255) / 256, 256, 0, stream>>>(Wih1, wih1b, GDIM * HDIM);
  conv_bf16<<<(FDIM * HDIM + 255) / 256, 256, 0, stream>>>(Wlin, wlinb, FDIM * HDIM);

  float* hn0 = out + 32768;
  float* hn1 = out + 32768 + 262144;
  float* cn0 = out + 32768 + 524288;
  float* cn1 = out + 32768 + 524288 + 262144;

  unsigned int gen_base = 0;
  for (int ch = 0; ch < T_STEPS / CH; ++ch) {
    int t0 = ch * CH;
    lstm_layer0_kernel<<<256, 512, 0, stream>>>(
        xbf, Wih0, Whh0, bih0, bhh0, slab, hx0, c0st, t0, CH, gen_base, hn0, cn0, bar, probe);
    gen_base += (unsigned int)CH;   // 1 probe + (CH-1) step stamps
    gemm_bt_xw<<<dim3(CH * 2, 32), 256, 0, stream>>>(
        slab + BATCH * HDIM, wih1b, xw1, HDIM);
    lstm_layer1_kernel<<<256, 512, 0, stream>>>(
        xw1, Whh1, bih1, bhh1, h1pp, c1st, t0, CH, gen_base, h1t0, hn1, cn1, bar, probe);
    gen_base += (unsigned int)CH;
  }

  y_kernel<<<256, 128, 0, stream>>>(h1t0, wlinb, blin, out);
}

// Round 8
// 3290.526 us; speedup vs baseline: 1.1012x; 1.0783x over previous
//
#include <hip/hip_runtime.h>
#include <stdint.h>

// ---------------------------------------------------------------------------
// 2-layer LSTM (T=256, B=256, F=128, H=1024) for MI355X (gfx950).
// R14: R13 recurrent kernels byte-identical; gemm_bt_xw upgraded from the
// 128^2 2-barrier m97-structure (~900 TF ceiling) to a 256^2 4-phase
// counted-vmcnt schedule (T2+T3+T4+T5 stack):
//   - BM=BN=256, BK=64, 8 waves (2Mx4N), acc[8][4], LDS 128KB dbuf.
//   - per K-tile: 4 phases, each {stage 2x8KB gll -> counted vmcnt ->
//     s_barrier -> ds_read subtile -> setprio(1) 16 MFMA setprio(0) ->
//     s_barrier}. vmcnt(4) at phase1, vmcnt(6) at phase3, NEVER 0 in-loop
//     (audited stage->consume mapping: B halves ph1/ph2, A quarters
//     {q0,q2} ph3, {q1,q3} ph4, consumed next iter ph1/ph3).
//   - LDS XOR-swizzle o^=((o>>7)&7)<<4 (in-row involution, R13-verified
//     family): ds_read 16-way -> 2-way; staging pre-applies the inverse on
//     the per-lane GLOBAL address (rule #21), LDS dest stays linear.
// ---------------------------------------------------------------------------

typedef __bf16 bf16x8 __attribute__((ext_vector_type(8)));
typedef float  f32x4  __attribute__((ext_vector_type(4)));
typedef unsigned short ushort8v __attribute__((ext_vector_type(8)));
typedef unsigned short ushort4v __attribute__((ext_vector_type(4)));
typedef unsigned short ushort2v __attribute__((ext_vector_type(2)));
typedef __attribute__((address_space(1))) unsigned int as1_u32;
typedef __attribute__((address_space(3))) unsigned int as3_u32;

#define T_STEPS 256
#define BATCH   256
#define HDIM    1024
#define GDIM    4096
#define FDIM    128
#define HXSLOT  (BATCH * HDIM)   // elements per blocked h slot (512KB)

static __device__ __forceinline__ float bf2f(unsigned short u) {
  union { unsigned int i; float f; } v; v.i = ((unsigned int)u) << 16; return v.f;
}
static __device__ __forceinline__ unsigned short f2bf(float f) {
  return __builtin_bit_cast(unsigned short, (__bf16)f);
}
static __device__ __forceinline__ float sigm(float x) { return 1.f / (1.f + __expf(-x)); }
static __device__ __forceinline__ float tanh_f(float x) { return 2.f / (1.f + __expf(-2.f * x)) - 1.f; }

// 2KB-sub-block bank swizzle (involution): flips byte bits 4-5 by row-pair.
static __device__ __forceinline__ int swz(int b) {
  return b ^ (((b >> 7) & 3) << 4);
}
// gemm LDS swizzle (involution): flips byte bits 4-6 by row (128B rows).
static __device__ __forceinline__ int gswz(int b) {
  return b ^ (((b >> 7) & 7) << 4);
}

static __device__ __forceinline__ void vl1_inv() {
  asm volatile("buffer_inv" ::: "memory");
}

__global__ void conv_bf16(const float* __restrict__ s, unsigned short* __restrict__ d, int n) {
  int i = blockIdx.x * 256 + threadIdx.x;
  if (i < n) d[i] = f2bf(s[i]);
}

__global__ void diag_kernel(float* out, int n, float v) {
  int i = blockIdx.x * 256 + threadIdx.x;
  if (i < n) out[i] = v;
}

// ------------------------- stamps / polls / flags ----------------------------
__device__ __forceinline__ void post_stamp(unsigned int* st, unsigned int gen, bool fast) {
  if (!fast) __builtin_amdgcn_fence(__ATOMIC_RELEASE, "agent");
  __hip_atomic_store(st, gen, __ATOMIC_RELAXED, __HIP_MEMORY_SCOPE_AGENT);
}

__device__ __forceinline__ void poll_all(unsigned int* stamps, unsigned int target) {
  unsigned int* p = stamps + (threadIdx.x & 31) * 32;
  for (unsigned int it = 0; it < (1u << 15); ++it) {
    unsigned int gv = __hip_atomic_load(p, __ATOMIC_RELAXED, __HIP_MEMORY_SCOPE_AGENT);
    if (__all((int)(gv - target) >= 0)) return;
    if (it > 16) __builtin_amdgcn_s_sleep(1);
  }
}

__device__ __forceinline__ void poll_mine(unsigned int* stamps, int g, int kh, unsigned int target) {
  unsigned int* p = stamps + (kh * 16 + g + 4 * ((int)threadIdx.x & 3)) * 32;
  for (unsigned int it = 0; it < (1u << 15); ++it) {
    unsigned int gv = __hip_atomic_load(p, __ATOMIC_RELAXED, __HIP_MEMORY_SCOPE_AGENT);
    if (__all((int)(gv - target) >= 0)) return;
    if (it > 64) __builtin_amdgcn_s_sleep(1);
  }
}

__device__ __forceinline__ void lds_spin(unsigned int* f, unsigned int need) {
  for (unsigned int it = 0; it < (1u << 15); ++it) {
    unsigned int v = __hip_atomic_load(f, __ATOMIC_ACQUIRE, __HIP_MEMORY_SCOPE_WORKGROUP);
    if ((int)(v - need) >= 0) return;
    if (it > 32) __builtin_amdgcn_s_sleep(1);
  }
}

// Stage this wave's 4 chunks (2KB each, contiguous in blocked h) into
// chunk-major As via global_load_lds width-16 (linear copy; the bank
// swizzle is baked into the producer's store addresses).
__device__ __forceinline__ void stage_chunks(const unsigned short* __restrict__ hsrc,
                                             unsigned short* AsPtr, int r0, int g, int kh, int lane) {
  #pragma unroll
  for (int q = 0; q < 4; ++q) {
    int c = kh * 16 + g + 4 * q;
    const char* src = (const char*)(hsrc + (size_t)c * 8192 + r0 * 32);
    char* dst = (char*)AsPtr + c * 2048;
    __builtin_amdgcn_global_load_lds((const as1_u32*)(src + lane * 16), (as3_u32*)dst, 16, 0, 0);
    __builtin_amdgcn_global_load_lds((const as1_u32*)(src + 1024 + lane * 16), (as3_u32*)(dst + 1024), 16, 0, 0);
  }
}

// --------------------------- gemm_bt: C = A @ B^T ---------------------------
// 256^2 tile, 4-phase counted-vmcnt schedule. A:(M,1024) M=grid.x*256,
// B:(4096,1024). Output xw[(bx*4096 + col)*256 + local_m].
__global__ __launch_bounds__(512, 2) void gemm_bt_xw(
    const unsigned short* __restrict__ A,
    const unsigned short* __restrict__ B,
    unsigned short* __restrict__ xw)
{
  const int tid = threadIdx.x, lane = tid & 63, wv = tid >> 6;   // 8 waves
  const int wm = wv & 1, wn = wv >> 1;                           // 2M x 4N
  const int quad = lane >> 4, l15 = lane & 15;
  const int m0 = blockIdx.x * 256;
  const int n0 = blockIdx.y * 256;

  __shared__ unsigned short Ab[2][16384];   // 32KB per buffer, swizzled
  __shared__ unsigned short Bb[2][16384];

  f32x4 acc[8][4];
  #pragma unroll
  for (int i = 0; i < 8; ++i)
    #pragma unroll
    for (int j = 0; j < 4; ++j) acc[i][j] = f32x4{0.f, 0.f, 0.f, 0.f};

  // stage one 8KB block (64 rows x 64 kcols) with pre-swizzled global source.
  // LDS dest linear (wave-uniform base + lane*16); global addr = row-major
  // with the in-row granule XOR applied (involution).
  #define G2L(dst8k, src, row_org, blk_row0, kt_)                                   \
    {                                                                               \
      int o_ = wv * 1024 + lane * 16;                                               \
      int tp_ = gswz(o_);                                                           \
      int row_ = (blk_row0) + (tp_ >> 7);                                           \
      const char* g_ = (const char*)((src) + (size_t)((row_org) + row_) * 1024)     \
                       + (kt_) * 128 + (tp_ & 127);                                 \
      __builtin_amdgcn_global_load_lds((const as1_u32*)g_,                          \
          (as3_u32*)((char*)(dst8k) + wv * 1024), 16, 0, 0);                        \
    }

  // prologue: stage K-tile 0 into buffer 0, full drain once.
  #pragma unroll
  for (int b4 = 0; b4 < 4; ++b4) G2L(&Bb[0][b4 * 4096], B, n0, b4 * 64, 0);
  #pragma unroll
  for (int q4 = 0; q4 < 4; ++q4) G2L(&Ab[0][q4 * 4096], A, m0, q4 * 64, 0);
  __syncthreads();

  bf16x8 af[4][2], bfr[4][2];

  #pragma unroll 1
  for (int kt = 0; kt < 16; ++kt) {
    const int cur = kt & 1, nxt = cur ^ 1;
    const bool st = (kt < 15);

    // ---------------- phase 1: B halves 0,1 for kt+1; consume B-all + A q(wm*2)
    if (st) { G2L(&Bb[nxt][0], B, n0, 0, kt + 1); G2L(&Bb[nxt][4096], B, n0, 64, kt + 1); }
    if (kt == 15)      asm volatile("s_waitcnt vmcnt(2)" ::: "memory");
    else if (kt > 0)   asm volatile("s_waitcnt vmcnt(4)" ::: "memory");
    __builtin_amdgcn_s_barrier();
    __builtin_amdgcn_sched_barrier(0);
    #pragma unroll
    for (int nt = 0; nt < 4; ++nt)
      #pragma unroll
      for (int kk = 0; kk < 2; ++kk) {
        int q = (wn * 64 + nt * 16 + l15) * 128 + kk * 64 + quad * 16;
        bfr[nt][kk] = *(const bf16x8*)((const char*)Bb[cur] + gswz(q));
      }
    #pragma unroll
    for (int mt = 0; mt < 4; ++mt)
      #pragma unroll
      for (int kk = 0; kk < 2; ++kk) {
        int q = (wm * 128 + mt * 16 + l15) * 128 + kk * 64 + quad * 16;
        af[mt][kk] = *(const bf16x8*)((const char*)Ab[cur] + gswz(q));
      }
    __builtin_amdgcn_s_setprio(1);
    #pragma unroll
    for (int mt = 0; mt < 4; ++mt)
      #pragma unroll
      for (int nt = 0; nt < 2; ++nt)
        #pragma unroll
        for (int kk = 0; kk < 2; ++kk)
          acc[mt][nt] = __builtin_amdgcn_mfma_f32_16x16x32_bf16(af[mt][kk], bfr[nt][kk], acc[mt][nt], 0, 0, 0);
    __builtin_amdgcn_s_setprio(0);
    __builtin_amdgcn_s_barrier();

    // ---------------- phase 2: B halves 2,3; pure MFMA (regs resident)
    if (st) { G2L(&Bb[nxt][8192], B, n0, 128, kt + 1); G2L(&Bb[nxt][12288], B, n0, 192, kt + 1); }
    __builtin_amdgcn_s_barrier();
    __builtin_amdgcn_s_setprio(1);
    #pragma unroll
    for (int mt = 0; mt < 4; ++mt)
      #pragma unroll
      for (int nt = 0; nt < 2; ++nt)
        #pragma unroll
        for (int kk = 0; kk < 2; ++kk)
          acc[mt][nt + 2] = __builtin_amdgcn_mfma_f32_16x16x32_bf16(af[mt][kk], bfr[nt + 2][kk], acc[mt][nt + 2], 0, 0, 0);
    __builtin_amdgcn_s_setprio(0);
    __builtin_amdgcn_s_barrier();

    // ---------------- phase 3: A quarters q0,q2; consume A q(wm*2+1)
    if (st) { G2L(&Ab[nxt][0], A, m0, 0, kt + 1); G2L(&Ab[nxt][8192], A, m0, 128, kt + 1); }
    if (kt == 15) asm volatile("s_waitcnt vmcnt(0)" ::: "memory");
    else          asm volatile("s_waitcnt vmcnt(6)" ::: "memory");
    __builtin_amdgcn_s_barrier();
    __builtin_amdgcn_sched_barrier(0);
    #pragma unroll
    for (int mt = 0; mt < 4; ++mt)
      #pragma unroll
      for (int kk = 0; kk < 2; ++kk) {
        int q = (wm * 128 + 64 + mt * 16 + l15) * 128 + kk * 64 + quad * 16;
        af[mt][kk] = *(const bf16x8*)((const char*)Ab[cur] + gswz(q));
      }
    __builtin_amdgcn_s_setprio(1);
    #pragma unroll
    for (int mt = 0; mt < 4; ++mt)
      #pragma unroll
      for (int nt = 0; nt < 2; ++nt)
        #pragma unroll
        for (int kk = 0; kk < 2; ++kk)
          acc[mt + 4][nt] = __builtin_amdgcn_mfma_f32_16x16x32_bf16(af[mt][kk], bfr[nt][kk], acc[mt + 4][nt], 0, 0, 0);
    __builtin_amdgcn_s_setprio(0);
    __builtin_amdgcn_s_barrier();

    // ---------------- phase 4: A quarters q1,q3; pure MFMA
    if (st) { G2L(&Ab[nxt][4096], A, m0, 64, kt + 1); G2L(&Ab[nxt][12288], A, m0, 192, kt + 1); }
    __builtin_amdgcn_s_barrier();
    __builtin_amdgcn_s_setprio(1);
    #pragma unroll
    for (int mt = 0; mt < 4; ++mt)
      #pragma unroll
      for (int nt = 0; nt < 2; ++nt)
        #pragma unroll
        for (int kk = 0; kk < 2; ++kk)
          acc[mt + 4][nt + 2] = __builtin_amdgcn_mfma_f32_16x16x32_bf16(af[mt][kk], bfr[nt + 2][kk], acc[mt + 4][nt + 2], 0, 0, 0);
    __builtin_amdgcn_s_setprio(0);
    __builtin_amdgcn_s_barrier();
  }
  #undef G2L

  // epilogue: C-write in the xw alt layout (tl = blockIdx.x, b = local m)
  #pragma unroll
  for (int mt = 0; mt < 8; ++mt) {
    int ml = wm * 128 + mt * 16 + quad * 4;
    #pragma unroll
    for (int nt = 0; nt < 4; ++nt) {
      int col = n0 + wn * 64 + nt * 16 + l15;
      ushort4v v;
      v.x = f2bf(acc[mt][nt][0]); v.y = f2bf(acc[mt][nt][1]);
      v.z = f2bf(acc[mt][nt][2]); v.w = f2bf(acc[mt][nt][3]);
      *(ushort4v*)(xw + ((size_t)blockIdx.x * GDIM + col) * BATCH + ml) = v;
    }
  }
}

// ---------------- probe: validate intra-XCD visibility for this group --------
__device__ __forceinline__ bool probe_chk(unsigned int* probeBuf, unsigned int* stamps,
                                          unsigned int salt, unsigned int target,
                                          unsigned int* flagLds) {
  const int wg = blockIdx.x, mi = wg & 7, ni = wg >> 3;
  const int tid = threadIdx.x;
  if (tid == 0) probeBuf[wg * 32] = salt ^ (unsigned int)wg;
  __syncthreads();   // drains token store to L2
  if (tid == 0)
    __hip_atomic_store(stamps + ni * 32, target, __ATOMIC_RELAXED, __HIP_MEMORY_SCOPE_AGENT);
  poll_all(stamps, target);
  vl1_inv();
  if (tid == 0) {
    unsigned int bad = 0;
    for (int k = 0; k < 32; ++k) {
      int member = mi + 8 * k;
      unsigned int v = probeBuf[member * 32];
      if (v != (salt ^ (unsigned int)member)) bad = 1;
    }
    *flagLds = bad;
  }
  __syncthreads();
  return (*flagLds == 0);
}

// --------------------------- layer 0: fused persistent chunk -----------------
// 256 WGs x 512 thr, 1/CU. WG (mi=wg&7, ni=wg>>3): rows [32mi,+32), cols [32ni,+32).
// Wave wv: gate g=wv&3, K-half kh=wv>>2. whh[2][16] slots in CONSUME order.
__global__ __launch_bounds__(512, 2) void lstm_layer0_kernel(
    const unsigned short* __restrict__ xbf,  // (T,B,F) bf16
    const float* __restrict__ Wih,           // (4096,128) fp32
    const float* __restrict__ Whh,           // (4096,1024) fp32
    const float* __restrict__ bih,
    const float* __restrict__ bhh,
    unsigned short* __restrict__ slab,       // (ch_len+1, B, H) bf16 row-major, gemm feed
    unsigned short* __restrict__ hx,         // 2-slot blocked+swizzled ping-pong
    float* __restrict__ cstate,              // (B,H) fp32
    int t0, int ch_len, unsigned int gen_base,
    float* __restrict__ dout_h,
    float* __restrict__ dout_c,
    unsigned int* __restrict__ bar,
    unsigned int* __restrict__ probe)
{
  const int tid = threadIdx.x, lane = tid & 63, wv = tid >> 6;   // wv 0..7
  const int quad = lane >> 4, l15 = lane & 15;
  const int g = wv & 3, kh = wv >> 2;
  const int wg = blockIdx.x;
  const int mi = wg & 7, ni = wg >> 3;
  const int r0 = mi * 32, hc0 = ni * 32;
  unsigned int* stamps = bar + mi * 1024;

  __shared__ unsigned short As[32 * 1024];   // chunk-major: [32 chunks][2KB swizzled]
  __shared__ float gbuf[8][32][33];          // 33: EW reads conflict-free
  __shared__ unsigned int cflag[8];          // per-(kh,g) stager flags
  __shared__ unsigned int flagLds;

  if (tid < 8) cflag[tid] = 0;

  // W_hh fragment, slots permuted into consume order:
  // slot sl -> chunk j(sl) = ((g + (sl>>2)) & 3) + 4*(sl&3)
  bf16x8 whh[2][16];
  #pragma unroll
  for (int nt = 0; nt < 2; ++nt) {
    #pragma unroll
    for (int sl = 0; sl < 16; ++sl) {
      int jj = ((g + (sl >> 2)) & 3) + 4 * (sl & 3);
      const float* wrow = Whh + (size_t)(g * HDIM + hc0 + nt * 16 + l15) * HDIM + kh * 512 + jj * 32 + quad * 8;
      f32x4 f0 = *(const f32x4*)(wrow);
      f32x4 f1 = *(const f32x4*)(wrow + 4);
      bf16x8 r;
      r[0] = (__bf16)f0[0]; r[1] = (__bf16)f0[1]; r[2] = (__bf16)f0[2]; r[3] = (__bf16)f0[3];
      r[4] = (__bf16)f1[0]; r[5] = (__bf16)f1[1]; r[6] = (__bf16)f1[2]; r[7] = (__bf16)f1[3];
      whh[nt][sl] = r;
    }
  }
  // W_ih fragment: K=128 split across kh (64 each)
  bf16x8 wih[2][2];
  #pragma unroll
  for (int nt = 0; nt < 2; ++nt) {
    const float* wrow = Wih + (size_t)(g * HDIM + hc0 + nt * 16 + l15) * FDIM + kh * 64 + quad * 8;
    #pragma unroll
    for (int kk = 0; kk < 2; ++kk) {
      f32x4 f0 = *(const f32x4*)(wrow + kk * 32);
      f32x4 f1 = *(const f32x4*)(wrow + kk * 32 + 4);
      bf16x8 r;
      r[0] = (__bf16)f0[0]; r[1] = (__bf16)f0[1]; r[2] = (__bf16)f0[2]; r[3] = (__bf16)f0[3];
      r[4] = (__bf16)f1[0]; r[5] = (__bf16)f1[1]; r[6] = (__bf16)f1[2]; r[7] = (__bf16)f1[3];
      wih[nt][kk] = r;
    }
  }

  const int hcl = tid & 31, rg2 = tid >> 5;
  float bias[4];
  #pragma unroll
  for (int b4 = 0; b4 < 4; ++b4)
    bias[b4] = bih[b4 * HDIM + hc0 + hcl] + bhh[b4 * HDIM + hc0 + hcl];

  float c[2];
  #pragma unroll
  for (int r = 0; r < 2; ++r)
    c[r] = (t0 == 0) ? 0.f : cstate[(size_t)(r0 + rg2 * 2 + r) * HDIM + hc0 + hcl];

  unsigned int salt = 0x9E3779B9u ^ (gen_base * 2654435761u);
  bool fast = probe_chk(probe, stamps, salt, gen_base + 1u, &flagLds);

  const int tend = t0 + ch_len;

  // prologue: cross-kernel h stage (blocked+swizzled hx from prev dispatch)
  if (t0 > 0) {
    stage_chunks(hx + (size_t)((t0 - 1) & 1) * HXSLOT, As, r0, g, kh, lane);
    asm volatile("s_waitcnt vmcnt(0)" ::: "memory");
    if (lane == 0)
      __hip_atomic_store(&cflag[kh * 4 + g], gen_base + 1u, __ATOMIC_RELEASE, __HIP_MEMORY_SCOPE_WORKGROUP);
  }

  // prologue: x-projection for the first step
  f32x4 acc[2][2];
  #pragma unroll
  for (int mt = 0; mt < 2; ++mt)
    #pragma unroll
    for (int nt = 0; nt < 2; ++nt) acc[mt][nt] = f32x4{0.f, 0.f, 0.f, 0.f};
  #pragma unroll
  for (int j = 0; j < 2; ++j) {
    bf16x8 af[2];
    #pragma unroll
    for (int mt = 0; mt < 2; ++mt)
      af[mt] = *(const bf16x8*)(xbf + (size_t)(t0 * BATCH + r0 + mt * 16 + l15) * FDIM + kh * 64 + j * 32 + quad * 8);
    #pragma unroll
    for (int mt = 0; mt < 2; ++mt)
      #pragma unroll
      for (int nt = 0; nt < 2; ++nt)
        acc[mt][nt] = __builtin_amdgcn_mfma_f32_16x16x32_bf16(af[mt], wih[nt][j], acc[mt][nt], 0, 0, 0);
  }

  #pragma unroll 1
  for (int t = t0; t < tend; ++t) {
    if (t > 0) {
      // consume 16 chunks in 4 stager-batches; self batch needs no spin.
      const unsigned int need = gen_base + 1u + (unsigned int)(t - t0);
      #pragma unroll
      for (int sl = 0; sl < 16; ++sl) {
        const int s = sl >> 2, q = sl & 3;
        int sg = (g + s) & 3;
        if (q == 0 && s > 0) lds_spin(&cflag[kh * 4 + sg], need);
        int cidx = kh * 16 + sg + 4 * q;
        bf16x8 af[2];
        #pragma unroll
        for (int mt = 0; mt < 2; ++mt) {
          int bo = (mt * 16 + l15) * 64 + quad * 16;
          bo = swz(bo);
          af[mt] = *(const bf16x8*)((const char*)As + cidx * 2048 + bo);
        }
        #pragma unroll
        for (int mt = 0; mt < 2; ++mt)
          #pragma unroll
          for (int nt = 0; nt < 2; ++nt)
            acc[mt][nt] = __builtin_amdgcn_mfma_f32_16x16x32_bf16(af[mt], whh[nt][sl], acc[mt][nt], 0, 0, 0);
      }
    }

    #pragma unroll
    for (int mt = 0; mt < 2; ++mt)
      #pragma unroll
      for (int nt = 0; nt < 2; ++nt) {
        int hl = nt * 16 + l15;
        int rq = mt * 16 + quad * 4;
        #pragma unroll
        for (int i = 0; i < 4; ++i)
          gbuf[wv][hl][rq + i] = acc[mt][nt][i];   // scalar: <=2-way at 33
      }
    __syncthreads();   // (A) gbuf visible; all As reads of step t complete

    unsigned short* hdst = slab + (size_t)(t - t0 + 1) * (BATCH * HDIM);
    unsigned short* hxd  = hx + (size_t)(t & 1) * HXSLOT;
    #pragma unroll
    for (int r = 0; r < 2; ++r) {
      int row = rg2 * 2 + r;
      float gi = gbuf[0][hcl][row] + gbuf[4][hcl][row] + bias[0];
      float gf = gbuf[1][hcl][row] + gbuf[5][hcl][row] + bias[1];
      float gg = gbuf[2][hcl][row] + gbuf[6][hcl][row] + bias[2];
      float go = gbuf[3][hcl][row] + gbuf[7][hcl][row] + bias[3];
      float iv = sigm(gi), fv = sigm(gf), gv = tanh_f(gg), ov = sigm(go);
      float cn = fv * c[r] + iv * gv;
      c[r] = cn;
      float hv = ov * tanh_f(cn);
      unsigned short hb = f2bf(hv);
      // blocked+swizzled hx: chunk ni, sub-block mi, swizzled byte offset
      int boff = swz(row * 64 + hcl * 2);
      hxd[ni * 8192 + mi * 1024 + (boff >> 1)] = hb;
      int gidx = (r0 + row) * HDIM + hc0 + hcl;
      hdst[gidx] = hb;       // gemm feed (row-major, unswizzled)
      if (t == tend - 1) cstate[gidx] = cn;
      if (t == T_STEPS - 1) { dout_h[gidx] = hv; dout_c[gidx] = cn; }
    }
    __syncthreads();   // (B) drains h stores (vmcnt 0) -> visible at L2

    if (t != tend - 1) {
      const unsigned int tgt = gen_base + 2u + (unsigned int)(t - t0);
      if (tid == 0) post_stamp(stamps + ni * 32, tgt, fast);

      // hoisted: x-projection for step t+1 (independent of h(t))
      #pragma unroll
      for (int mt = 0; mt < 2; ++mt)
        #pragma unroll
        for (int nt = 0; nt < 2; ++nt) acc[mt][nt] = f32x4{0.f, 0.f, 0.f, 0.f};
      #pragma unroll
      for (int j = 0; j < 2; ++j) {
        bf16x8 af[2];
        #pragma unroll
        for (int mt = 0; mt < 2; ++mt)
          af[mt] = *(const bf16x8*)(xbf + (size_t)((t + 1) * BATCH + r0 + mt * 16 + l15) * FDIM + kh * 64 + j * 32 + quad * 8);
        #pragma unroll
        for (int mt = 0; mt < 2; ++mt)
          #pragma unroll
          for (int nt = 0; nt < 2; ++nt)
            acc[mt][nt] = __builtin_amdgcn_mfma_f32_16x16x32_bf16(af[mt], wih[nt][j], acc[mt][nt], 0, 0, 0);
      }

      // exchange: wait only for MY 4 producers, stage my chunks, flag.
      poll_mine(stamps, g, kh, tgt);
      if (fast) vl1_inv();
      else __builtin_amdgcn_fence(__ATOMIC_ACQUIRE, "agent");
      stage_chunks(hx + (size_t)(t & 1) * HXSLOT, As, r0, g, kh, lane);
      asm volatile("s_waitcnt vmcnt(0)" ::: "memory");
      if (lane == 0)
        __hip_atomic_store(&cflag[kh * 4 + g], tgt, __ATOMIC_RELEASE, __HIP_MEMORY_SCOPE_WORKGROUP);
    }
  }
}

// --------------------------- layer 1: persistent chunk ----------------------
__global__ __launch_bounds__(512, 2) void lstm_layer1_kernel(
    const unsigned short* __restrict__ xw,   // (ch_len, 4096, 256) bf16
    const float* __restrict__ Whh,
    const float* __restrict__ bih,
    const float* __restrict__ bhh,
    unsigned short* __restrict__ hpp,        // 2-slot blocked+swizzled ping-pong
    float* __restrict__ cstate,
    int t0, int ch_len, unsigned int gen_base,
    unsigned short* __restrict__ h1t0,
    float* __restrict__ dout_h,
    float* __restrict__ dout_c,
    unsigned int* __restrict__ bar,
    unsigned int* __restrict__ probe)
{
  const int tid = threadIdx.x, lane = tid & 63, wv = tid >> 6;
  const int quad = lane >> 4, l15 = lane & 15;
  const int g = wv & 3, kh = wv >> 2;
  const int wg = blockIdx.x;
  const int mi = wg & 7, ni = wg >> 3;
  const int r0 = mi * 32, hc0 = ni * 32;
  unsigned int* stamps = bar + mi * 1024;

  __shared__ unsigned short As[32 * 1024];
  __shared__ float gbuf[8][32][33];
  __shared__ unsigned int cflag[8];
  __shared__ unsigned int flagLds;

  if (tid < 8) cflag[tid] = 0;

  bf16x8 whh[2][16];
  #pragma unroll
  for (int nt = 0; nt < 2; ++nt) {
    #pragma unroll
    for (int sl = 0; sl < 16; ++sl) {
      int jj = ((g + (sl >> 2)) & 3) + 4 * (sl & 3);
      const float* wrow = Whh + (size_t)(g * HDIM + hc0 + nt * 16 + l15) * HDIM + kh * 512 + jj * 32 + quad * 8;
      f32x4 f0 = *(const f32x4*)(wrow);
      f32x4 f1 = *(const f32x4*)(wrow + 4);
      bf16x8 r;
      r[0] = (__bf16)f0[0]; r[1] = (__bf16)f0[1]; r[2] = (__bf16)f0[2]; r[3] = (__bf16)f0[3];
      r[4] = (__bf16)f1[0]; r[5] = (__bf16)f1[1]; r[6] = (__bf16)f1[2]; r[7] = (__bf16)f1[3];
      whh[nt][sl] = r;
    }
  }

  const int hcl = tid & 31, rg2 = tid >> 5;
  float bias[4];
  #pragma unroll
  for (int b4 = 0; b4 < 4; ++b4)
    bias[b4] = bih[b4 * HDIM + hc0 + hcl] + bhh[b4 * HDIM + hc0 + hcl];

  float c[2];
  #pragma unroll
  for (int r = 0; r < 2; ++r)
    c[r] = (t0 == 0) ? 0.f : cstate[(size_t)(r0 + rg2 * 2 + r) * HDIM + hc0 + hcl];

  unsigned int salt = 0xB5297A4Du ^ (gen_base * 2654435761u);
  bool fast = probe_chk(probe, stamps, salt, gen_base + 1u, &flagLds);

  const int tend = t0 + ch_len;

  if (t0 > 0) {
    stage_chunks(hpp + (size_t)((t0 - 1) & 1) * HXSLOT, As, r0, g, kh, lane);
    asm volatile("s_waitcnt vmcnt(0)" ::: "memory");
    if (lane == 0)
      __hip_atomic_store(&cflag[kh * 4 + g], gen_base + 1u, __ATOMIC_RELEASE, __HIP_MEMORY_SCOPE_WORKGROUP);
  }

  float xwv[4][2];
  #pragma unroll
  for (int g4 = 0; g4 < 4; ++g4) {
    const unsigned short* xp =
        xw + ((size_t)0 * GDIM + g4 * HDIM + hc0 + hcl) * BATCH + r0 + rg2 * 2;
    ushort2v u = *(const ushort2v*)xp;
    xwv[g4][0] = bf2f(u.x); xwv[g4][1] = bf2f(u.y);
  }

  #pragma unroll 1
  for (int t = t0; t < tend; ++t) {
    f32x4 acc[2][2];
    #pragma unroll
    for (int mt = 0; mt < 2; ++mt)
      #pragma unroll
      for (int nt = 0; nt < 2; ++nt) acc[mt][nt] = f32x4{0.f, 0.f, 0.f, 0.f};

    if (t > 0) {
      const unsigned int need = gen_base + 1u + (unsigned int)(t - t0);
      #pragma unroll
      for (int sl = 0; sl < 16; ++sl) {
        const int s = sl >> 2, q = sl & 3;
        int sg = (g + s) & 3;
        if (q == 0 && s > 0) lds_spin(&cflag[kh * 4 + sg], need);
        int cidx = kh * 16 + sg + 4 * q;
        bf16x8 af[2];
        #pragma unroll
        for (int mt = 0; mt < 2; ++mt) {
          int bo = (mt * 16 + l15) * 64 + quad * 16;
          bo = swz(bo);
          af[mt] = *(const bf16x8*)((const char*)As + cidx * 2048 + bo);
        }
        #pragma unroll
        for (int mt = 0; mt < 2; ++mt)
          #pragma unroll
          for (int nt = 0; nt < 2; ++nt)
            acc[mt][nt] = __builtin_amdgcn_mfma_f32_16x16x32_bf16(af[mt], whh[nt][sl], acc[mt][nt], 0, 0, 0);
      }
    }

    #pragma unroll
    for (int mt = 0; mt < 2; ++mt)
      #pragma unroll
      for (int nt = 0; nt < 2; ++nt) {
        int hl = nt * 16 + l15;
        int rq = mt * 16 + quad * 4;
        #pragma unroll
        for (int i = 0; i < 4; ++i)
          gbuf[wv][hl][rq + i] = acc[mt][nt][i];
      }
    __syncthreads();   // (A)

    unsigned short* hxd = hpp + (size_t)(t & 1) * HXSLOT;
    #pragma unroll
    for (int r = 0; r < 2; ++r) {
      int row = rg2 * 2 + r;
      float gi = gbuf[0][hcl][row] + gbuf[4][hcl][row] + xwv[0][r] + bias[0];
      float gf = gbuf[1][hcl][row] + gbuf[5][hcl][row] + xwv[1][r] + bias[1];
      float gg = gbuf[2][hcl][row] + gbuf[6][hcl][row] + xwv[2][r] + bias[2];
      float go = gbuf[3][hcl][row] + gbuf[7][hcl][row] + xwv[3][r] + bias[3];
      float iv = sigm(gi), fv = sigm(gf), gv = tanh_f(gg), ov = sigm(go);
      float cn = fv * c[r] + iv * gv;
      c[r] = cn;
      float hv = ov * tanh_f(cn);
      unsigned short hb = f2bf(hv);
      int boff = swz(row * 64 + hcl * 2);
      hxd[ni * 8192 + mi * 1024 + (boff >> 1)] = hb;
      int gidx = (r0 + row) * HDIM + hc0 + hcl;
      if (h1t0 != nullptr && t == 0) h1t0[gidx] = hb;
      if (t == tend - 1) cstate[gidx] = cn;
      if (t == T_STEPS - 1) { dout_h[gidx] = hv; dout_c[gidx] = cn; }
    }
    __syncthreads();   // (B)

    if (t != tend - 1) {
      const unsigned int tgt = gen_base + 2u + (unsigned int)(t - t0);
      if (tid == 0) post_stamp(stamps + ni * 32, tgt, fast);

      // hoisted: xw loads for step t+1
      #pragma unroll
      for (int g4 = 0; g4 < 4; ++g4) {
        const unsigned short* xp =
            xw + ((size_t)(t + 1 - t0) * GDIM + g4 * HDIM + hc0 + hcl) * BATCH + r0 + rg2 * 2;
        ushort2v u = *(const ushort2v*)xp;
        xwv[g4][0] = bf2f(u.x); xwv[g4][1] = bf2f(u.y);
      }

      poll_mine(stamps, g, kh, tgt);
      if (fast) vl1_inv();
      else __builtin_amdgcn_fence(__ATOMIC_ACQUIRE, "agent");
      stage_chunks(hpp + (size_t)(t & 1) * HXSLOT, As, r0, g, kh, lane);
      asm volatile("s_waitcnt vmcnt(0)" ::: "memory");
      if (lane == 0)
        __hip_atomic_store(&cflag[kh * 4 + g], tgt, __ATOMIC_RELEASE, __HIP_MEMORY_SCOPE_WORKGROUP);
    }
  }
}

__global__ void y_kernel(const unsigned short* __restrict__ h1t0,
                         const unsigned short* __restrict__ wlin,
                         const float* __restrict__ blin,
                         float* __restrict__ y)
{
  int b = blockIdx.x;
  int f = threadIdx.x;
  const ushort8v* hp = (const ushort8v*)(h1t0 + (size_t)b * HDIM);
  const ushort8v* wp = (const ushort8v*)(wlin + (size_t)f * HDIM);
  float acc = 0.f;
  for (int i = 0; i < HDIM / 8; ++i) {
    ushort8v hv = hp[i], wvv = wp[i];
    #pragma unroll
    for (int j = 0; j < 8; ++j) acc += bf2f(hv[j]) * bf2f(wvv[j]);
  }
  y[b * FDIM + f] = acc + blin[f];
}

// ---------------------------------------------------------------------------
extern "C" void kernel_launch(void* const* d_in, const int* in_sizes, int n_in,
                              void* d_out, int out_size, void* d_ws, size_t ws_size,
                              hipStream_t stream) {
  (void)in_sizes; (void)n_in; (void)out_size;
  const float* x    = (const float*)d_in[0];
  const float* Wih0 = (const float*)d_in[1];
  const float* Whh0 = (const float*)d_in[2];
  const float* bih0 = (const float*)d_in[3];
  const float* bhh0 = (const float*)d_in[4];
  const float* Wih1 = (const float*)d_in[5];
  const float* Whh1 = (const float*)d_in[6];
  const float* bih1 = (const float*)d_in[7];
  const float* bhh1 = (const float*)d_in[8];
  const float* Wlin = (const float*)d_in[9];
  const float* blin = (const float*)d_in[10];
  float* out = (float*)d_out;

  const size_t SZ_BAR   = 32768;   // 8 groups x 32 stamps x 128B
  const size_t SZ_PROBE = 32768;
  const size_t SZ_XBF   = (size_t)T_STEPS * BATCH * FDIM * 2;
  const size_t SZ_WIH1  = (size_t)GDIM * HDIM * 2;
  const size_t SZ_WLIN  = (size_t)FDIM * HDIM * 2;
  const size_t SZ_HPP   = (size_t)2 * BATCH * HDIM * 2;
  const size_t SZ_HX    = (size_t)2 * BATCH * HDIM * 2;
  const size_t SZ_H1T0  = (size_t)BATCH * HDIM * 2;
  const size_t SZ_CST   = (size_t)BATCH * HDIM * 4;
  const size_t SLOT     = (size_t)BATCH * HDIM * 2;
  const size_t fixed = SZ_BAR + SZ_PROBE + SZ_XBF + SZ_WIH1 + SZ_WLIN + SZ_HPP + SZ_HX + SZ_H1T0 + 2 * SZ_CST;

  int CH = 0;
  const int cands[7] = {256, 128, 64, 32, 16, 8, 4};
  for (int i = 0; i < 7; ++i) {
    int c = cands[i];
    size_t need = fixed + (size_t)(c + 1) * SLOT + (size_t)c * GDIM * BATCH * 2;
    if (need <= ws_size) { CH = c; break; }
  }
  if (CH == 0) {
    float v = 1.0e6f + (float)(ws_size >> 20);
    diag_kernel<<<(32768 + 255) / 256, 256, 0, stream>>>(out, 32768, v);
    return;
  }

  char* ws = (char*)d_ws;
  size_t o = 0;
  unsigned int*   bar   = (unsigned int*)(ws + o);    o += SZ_BAR;
  unsigned int*   probe = (unsigned int*)(ws + o);    o += SZ_PROBE;
  unsigned short* xbf   = (unsigned short*)(ws + o);  o += SZ_XBF;
  unsigned short* wih1b = (unsigned short*)(ws + o);  o += SZ_WIH1;
  unsigned short* wlinb = (unsigned short*)(ws + o);  o += SZ_WLIN;
  unsigned short* h1pp  = (unsigned short*)(ws + o);  o += SZ_HPP;
  unsigned short* hx0   = (unsigned short*)(ws + o);  o += SZ_HX;
  unsigned short* h1t0  = (unsigned short*)(ws + o);  o += SZ_H1T0;
  float*          c0st  = (float*)(ws + o);           o += SZ_CST;
  float*          c1st  = (float*)(ws + o);           o += SZ_CST;
  unsigned short* slab  = (unsigned short*)(ws + o);  o += (size_t)(CH + 1) * SLOT;
  unsigned short* xw1   = (unsigned short*)(ws + o);  o += (size_t)CH * GDIM * BATCH * 2;

  hipMemsetAsync(bar, 0, SZ_BAR, stream);

  conv_bf16<<<(T_STEPS * BATCH * FDIM + 255) / 256, 256, 0, stream>>>(x, xbf, T_STEPS * BATCH * FDIM);
  conv_bf16<<<(GDIM * HDIM + 255) / 256, 256, 0, stream>>>(Wih1, wih1b, GDIM * HDIM);
  conv_bf16<<<(FDIM * HDIM + 255) / 256, 256, 0, stream>>>(Wlin, wlinb, FDIM * HDIM);

  float* hn0 = out + 32768;
  float* hn1 = out + 32768 + 262144;
  float* cn0 = out + 32768 + 524288;
  float* cn1 = out + 32768 + 524288 + 262144;

  unsigned int gen_base = 0;
  for (int ch = 0; ch < T_STEPS / CH; ++ch) {
    int t0 = ch * CH;
    lstm_layer0_kernel<<<256, 512, 0, stream>>>(
        xbf, Wih0, Whh0, bih0, bhh0, slab, hx0, c0st, t0, CH, gen_base, hn0, cn0, bar, probe);
    gen_base += (unsigned int)CH;   // 1 probe + (CH-1) step stamps
    gemm_bt_xw<<<dim3(CH, 16), 512, 0, stream>>>(
        slab + BATCH * HDIM, wih1b, xw1);
    lstm_layer1_kernel<<<256, 512, 0, stream>>>(
        xw1, Whh1, bih1, bhh1, h1pp, c1st, t0, CH, gen_base, h1t0, hn1, cn1, bar, probe);
    gen_base += (unsigned int)CH;
  }

  y_kernel<<<256, 128, 0, stream>>>(h1t0, wlinb, blin, out);
}